// Round 1
// baseline (2499.608 us; speedup 1.0000x reference)
//
#include <hip/hip_runtime.h>
#include <math.h>

#define B_ 2
#define T_ 2048
#define D_ 1024
#define H_ 16
#define HS_ 64
#define BT_ (B_*T_)
#define EPS_ 1e-5f
#define SCALE_ 0.03125f  // D^-0.5 = 1/32
#define NEG_ (-1e30f)

// ---------------- LayerNorm: one block per row ----------------
__global__ __launch_bounds__(256) void ln_kernel(const float* __restrict__ x,
        const float* __restrict__ g, const float* __restrict__ b,
        float* __restrict__ out) {
    int row = blockIdx.x;
    int tid = threadIdx.x;
    const float* xr = x + (size_t)row * D_;
    float4 v = *(const float4*)(xr + tid * 4);
    __shared__ float red[256];
    red[tid] = v.x + v.y + v.z + v.w;
    __syncthreads();
    for (int st = 128; st > 0; st >>= 1) {
        if (tid < st) red[tid] += red[tid + st];
        __syncthreads();
    }
    float mean = red[0] * (1.0f / D_);
    __syncthreads();
    float dx = v.x - mean, dy = v.y - mean, dz = v.z - mean, dw = v.w - mean;
    red[tid] = dx*dx + dy*dy + dz*dz + dw*dw;
    __syncthreads();
    for (int st = 128; st > 0; st >>= 1) {
        if (tid < st) red[tid] += red[tid + st];
        __syncthreads();
    }
    float rstd = rsqrtf(red[0] * (1.0f / D_) + EPS_);
    float4 gv = *(const float4*)(g + tid * 4);
    float4 bv = *(const float4*)(b + tid * 4);
    float4 o;
    o.x = dx * rstd * gv.x + bv.x;
    o.y = dy * rstd * gv.y + bv.y;
    o.z = dz * rstd * gv.z + bv.z;
    o.w = dw * rstd * gv.w + bv.w;
    *(float4*)(out + (size_t)row * D_ + tid * 4) = o;
}

// ---------------- Generic 64x64 fp32 tiled GEMM ----------------
// C[M,N] = A[M,K] @ Bw[K,N] (+bias[col]) (+res[row,col]) (relu)
template<bool BIAS, bool RES, bool RELU>
__global__ __launch_bounds__(256) void gemm64(const float* __restrict__ A,
        const float* __restrict__ Bw, const float* __restrict__ bias,
        const float* __restrict__ res, float* __restrict__ C,
        int M, int N, int K) {
    __shared__ float Ast[16][64];   // [k][m]
    __shared__ float Bs[16][64];    // [k][n]
    int tid = threadIdx.x;
    int m0 = blockIdx.y * 64, n0 = blockIdx.x * 64;
    int tx = tid & 15, ty = tid >> 4;
    int arow = tid >> 2, ac4 = (tid & 3) * 4;
    int brow = tid >> 4, bc4 = (tid & 15) * 4;
    float acc[4][4] = {};
    for (int kt = 0; kt < K; kt += 16) {
        float4 av = *(const float4*)(A + (size_t)(m0 + arow) * K + kt + ac4);
        float4 bv = *(const float4*)(Bw + (size_t)(kt + brow) * N + n0 + bc4);
        Ast[ac4 + 0][arow] = av.x;
        Ast[ac4 + 1][arow] = av.y;
        Ast[ac4 + 2][arow] = av.z;
        Ast[ac4 + 3][arow] = av.w;
        *(float4*)&Bs[brow][bc4] = bv;
        __syncthreads();
        #pragma unroll
        for (int kk = 0; kk < 16; ++kk) {
            float4 a4 = *(float4*)&Ast[kk][ty * 4];
            float4 b4 = *(float4*)&Bs[kk][tx * 4];
            float a[4] = {a4.x, a4.y, a4.z, a4.w};
            float b[4] = {b4.x, b4.y, b4.z, b4.w};
            #pragma unroll
            for (int i = 0; i < 4; ++i)
                #pragma unroll
                for (int j = 0; j < 4; ++j)
                    acc[i][j] = fmaf(a[i], b[j], acc[i][j]);
        }
        __syncthreads();
    }
    #pragma unroll
    for (int i = 0; i < 4; ++i) {
        int row = m0 + ty * 4 + i;
        #pragma unroll
        for (int j = 0; j < 4; ++j) {
            int col = n0 + tx * 4 + j;
            float vv = acc[i][j];
            if (BIAS) vv += bias[col];
            if (RES)  vv += res[(size_t)row * N + col];
            if (RELU) vv = fmaxf(vv, 0.0f);
            C[(size_t)row * N + col] = vv;
        }
    }
}

// ---------------- QKV projection: per-head GEMM ----------------
// grid (BT/64, H, 3); out layout [B,H,T,HS]
__global__ __launch_bounds__(256) void qkv_kernel(const float* __restrict__ xn,
        const float* __restrict__ Wq, const float* __restrict__ Wk,
        const float* __restrict__ Wv,
        float* __restrict__ q, float* __restrict__ k, float* __restrict__ v) {
    int mt = blockIdx.x;
    int h = blockIdx.y;
    int sel = blockIdx.z;
    const float* W = (sel == 0 ? Wq : sel == 1 ? Wk : Wv) + (size_t)h * D_ * HS_;
    float* out = (sel == 0 ? q : sel == 1 ? k : v);
    __shared__ float Ast[16][64];
    __shared__ float Bs[16][64];
    int tid = threadIdx.x;
    int m0 = mt * 64;
    int tx = tid & 15, ty = tid >> 4;
    int arow = tid >> 2, ac4 = (tid & 3) * 4;
    int brow = tid >> 4, bc4 = (tid & 15) * 4;
    float acc[4][4] = {};
    for (int kt = 0; kt < D_; kt += 16) {
        float4 av = *(const float4*)(xn + (size_t)(m0 + arow) * D_ + kt + ac4);
        float4 bv = *(const float4*)(W + (size_t)(kt + brow) * HS_ + bc4);
        Ast[ac4 + 0][arow] = av.x;
        Ast[ac4 + 1][arow] = av.y;
        Ast[ac4 + 2][arow] = av.z;
        Ast[ac4 + 3][arow] = av.w;
        *(float4*)&Bs[brow][bc4] = bv;
        __syncthreads();
        #pragma unroll
        for (int kk = 0; kk < 16; ++kk) {
            float4 a4 = *(float4*)&Ast[kk][ty * 4];
            float4 b4 = *(float4*)&Bs[kk][tx * 4];
            float a[4] = {a4.x, a4.y, a4.z, a4.w};
            float b[4] = {b4.x, b4.y, b4.z, b4.w};
            #pragma unroll
            for (int i = 0; i < 4; ++i)
                #pragma unroll
                for (int j = 0; j < 4; ++j)
                    acc[i][j] = fmaf(a[i], b[j], acc[i][j]);
        }
        __syncthreads();
    }
    #pragma unroll
    for (int i = 0; i < 4; ++i) {
        int row = m0 + ty * 4 + i;          // row in [BT)
        int bb = row / T_, tt = row % T_;
        #pragma unroll
        for (int j = 0; j < 4; ++j) {
            int e = tx * 4 + j;
            out[((size_t)(bb * H_ + h) * T_ + tt) * HS_ + e] = acc[i][j];
        }
    }
}

// ---------------- Attention pass 1: column (key-axis over q) stats ----------
// m_k = max_{q>=k} s[q,k], l_k = sum_{q>=k} exp(s[q,k]-m_k);  s = (q.k)*SCALE
// grid (T/64 key tiles, B*H)
__global__ __launch_bounds__(256) void attn_pass1(const float* __restrict__ q,
        const float* __restrict__ k, float* __restrict__ mout,
        float* __restrict__ lout) {
    int kt = blockIdx.x;
    int bh = blockIdx.y;
    const float* qb = q + (size_t)bh * T_ * HS_;
    const float* kb = k + (size_t)bh * T_ * HS_;
    __shared__ float Ks[64][65], Qs[64][65];
    __shared__ float red[16][64];
    __shared__ float mcol[64], lcol[64], nm[64];
    int tid = threadIdx.x;
    int tx = tid & 15, ty = tid >> 4;
    #pragma unroll
    for (int i = 0; i < 4; ++i) {
        int idx = tid + i * 256;
        int r = idx >> 4, e4 = (idx & 15) * 4;
        float4 vv = *(const float4*)(kb + (size_t)(kt * 64 + r) * HS_ + e4);
        Ks[r][e4] = vv.x; Ks[r][e4+1] = vv.y; Ks[r][e4+2] = vv.z; Ks[r][e4+3] = vv.w;
    }
    if (tid < 64) { mcol[tid] = NEG_; lcol[tid] = 0.0f; }
    __syncthreads();
    for (int qt = kt; qt < T_ / 64; ++qt) {
        #pragma unroll
        for (int i = 0; i < 4; ++i) {
            int idx = tid + i * 256;
            int r = idx >> 4, e4 = (idx & 15) * 4;
            float4 vv = *(const float4*)(qb + (size_t)(qt * 64 + r) * HS_ + e4);
            Qs[r][e4] = vv.x; Qs[r][e4+1] = vv.y; Qs[r][e4+2] = vv.z; Qs[r][e4+3] = vv.w;
        }
        __syncthreads();
        float s[4][4] = {};
        #pragma unroll 16
        for (int e = 0; e < 64; ++e) {
            float a[4], b[4];
            #pragma unroll
            for (int i = 0; i < 4; ++i) a[i] = Qs[ty * 4 + i][e];
            #pragma unroll
            for (int j = 0; j < 4; ++j) b[j] = Ks[tx * 4 + j][e];
            #pragma unroll
            for (int i = 0; i < 4; ++i)
                #pragma unroll
                for (int j = 0; j < 4; ++j)
                    s[i][j] = fmaf(a[i], b[j], s[i][j]);
        }
        float pm[4];
        #pragma unroll
        for (int j = 0; j < 4; ++j) {
            int kglob = kt * 64 + tx * 4 + j;
            pm[j] = NEG_;
            #pragma unroll
            for (int i = 0; i < 4; ++i) {
                int qglob = qt * 64 + ty * 4 + i;
                s[i][j] = (qglob >= kglob) ? s[i][j] * SCALE_ : NEG_;
                pm[j] = fmaxf(pm[j], s[i][j]);
            }
            red[ty][tx * 4 + j] = pm[j];
        }
        __syncthreads();
        if (tid < 64) {
            float tm = red[0][tid];
            #pragma unroll
            for (int r = 1; r < 16; ++r) tm = fmaxf(tm, red[r][tid]);
            float newm = fmaxf(mcol[tid], tm);
            lcol[tid] *= expf(mcol[tid] - newm);
            mcol[tid] = newm;
            nm[tid] = newm;
        }
        __syncthreads();
        #pragma unroll
        for (int j = 0; j < 4; ++j) {
            float nmv = nm[tx * 4 + j];
            float ps = 0.0f;
            #pragma unroll
            for (int i = 0; i < 4; ++i) ps += expf(s[i][j] - nmv);
            red[ty][tx * 4 + j] = ps;
        }
        __syncthreads();
        if (tid < 64) {
            float sm = 0.0f;
            #pragma unroll
            for (int r = 0; r < 16; ++r) sm += red[r][tid];
            lcol[tid] += sm;
        }
        __syncthreads();   // also protects Qs for next iteration
    }
    if (tid < 64) {
        mout[(size_t)bh * T_ + kt * 64 + tid] = mcol[tid];
        lout[(size_t)bh * T_ + kt * 64 + tid] = lcol[tid];
    }
}

// ---------------- Attention pass 2: O = sum_k w[q,k] V[k] -------------------
// grid (T/64 query tiles, B*H); writes concat-head layout [B,T,D]
__global__ __launch_bounds__(256) void attn_pass2(const float* __restrict__ q,
        const float* __restrict__ k, const float* __restrict__ v,
        const float* __restrict__ mio, const float* __restrict__ lio,
        float* __restrict__ attn_cat) {
    int qt = blockIdx.x;
    int bh = blockIdx.y;
    int bb = bh / H_, hh = bh % H_;
    const float* qb = q + (size_t)bh * T_ * HS_;
    const float* kb = k + (size_t)bh * T_ * HS_;
    const float* vb = v + (size_t)bh * T_ * HS_;
    __shared__ float Qs[64][65], Ks[64][65], Vs[64][65];
    __shared__ float mt_[64], lt_[64];
    int tid = threadIdx.x;
    int tx = tid & 15, ty = tid >> 4;
    #pragma unroll
    for (int i = 0; i < 4; ++i) {
        int idx = tid + i * 256;
        int r = idx >> 4, e4 = (idx & 15) * 4;
        float4 vv = *(const float4*)(qb + (size_t)(qt * 64 + r) * HS_ + e4);
        Qs[r][e4] = vv.x; Qs[r][e4+1] = vv.y; Qs[r][e4+2] = vv.z; Qs[r][e4+3] = vv.w;
    }
    float o[4][4] = {};
    for (int kt2 = 0; kt2 <= qt; ++kt2) {
        __syncthreads();   // protect Ks/Vs (prev GEMM) and Qs (first iter load)
        #pragma unroll
        for (int i = 0; i < 4; ++i) {
            int idx = tid + i * 256;
            int r = idx >> 4, e4 = (idx & 15) * 4;
            float4 kv = *(const float4*)(kb + (size_t)(kt2 * 64 + r) * HS_ + e4);
            Ks[r][e4] = kv.x; Ks[r][e4+1] = kv.y; Ks[r][e4+2] = kv.z; Ks[r][e4+3] = kv.w;
            float4 vv = *(const float4*)(vb + (size_t)(kt2 * 64 + r) * HS_ + e4);
            Vs[r][e4] = vv.x; Vs[r][e4+1] = vv.y; Vs[r][e4+2] = vv.z; Vs[r][e4+3] = vv.w;
        }
        if (tid < 64) {
            mt_[tid] = mio[(size_t)bh * T_ + kt2 * 64 + tid];
            lt_[tid] = 1.0f / lio[(size_t)bh * T_ + kt2 * 64 + tid];
        }
        __syncthreads();
        float s[4][4] = {};
        #pragma unroll 16
        for (int e = 0; e < 64; ++e) {
            float a[4], b[4];
            #pragma unroll
            for (int i = 0; i < 4; ++i) a[i] = Qs[ty * 4 + i][e];
            #pragma unroll
            for (int j = 0; j < 4; ++j) b[j] = Ks[tx * 4 + j][e];
            #pragma unroll
            for (int i = 0; i < 4; ++i)
                #pragma unroll
                for (int j = 0; j < 4; ++j)
                    s[i][j] = fmaf(a[i], b[j], s[i][j]);
        }
        float w[4][4];
        #pragma unroll
        for (int j = 0; j < 4; ++j) {
            int kglob = kt2 * 64 + tx * 4 + j;
            float mv = mt_[tx * 4 + j], lv = lt_[tx * 4 + j];
            #pragma unroll
            for (int i = 0; i < 4; ++i) {
                int qglob = qt * 64 + ty * 4 + i;
                w[i][j] = (qglob >= kglob) ? expf(s[i][j] * SCALE_ - mv) * lv : 0.0f;
            }
        }
        __syncthreads();   // everyone done reading Ks
        #pragma unroll
        for (int i = 0; i < 4; ++i)
            #pragma unroll
            for (int j = 0; j < 4; ++j)
                Ks[ty * 4 + i][tx * 4 + j] = w[i][j];   // reuse Ks as W tile
        __syncthreads();
        #pragma unroll 8
        for (int kk = 0; kk < 64; ++kk) {
            float wa[4], vb4[4];
            #pragma unroll
            for (int i = 0; i < 4; ++i) wa[i] = Ks[ty * 4 + i][kk];
            #pragma unroll
            for (int j = 0; j < 4; ++j) vb4[j] = Vs[kk][tx * 4 + j];
            #pragma unroll
            for (int i = 0; i < 4; ++i)
                #pragma unroll
                for (int j = 0; j < 4; ++j)
                    o[i][j] = fmaf(wa[i], vb4[j], o[i][j]);
        }
    }
    #pragma unroll
    for (int i = 0; i < 4; ++i) {
        int tt = qt * 64 + ty * 4 + i;
        #pragma unroll
        for (int j = 0; j < 4; ++j) {
            attn_cat[((size_t)(bb * T_ + tt)) * D_ + hh * HS_ + tx * 4 + j] = o[i][j];
        }
    }
}

extern "C" void kernel_launch(void* const* d_in, const int* in_sizes, int n_in,
                              void* d_out, int out_size, void* d_ws, size_t ws_size,
                              hipStream_t stream) {
    const float* x     = (const float*)d_in[0];
    const float* Wq    = (const float*)d_in[1];
    const float* Wk    = (const float*)d_in[2];
    const float* Wv    = (const float*)d_in[3];
    const float* Wproj = (const float*)d_in[4];
    const float* bproj = (const float*)d_in[5];
    const float* W1    = (const float*)d_in[6];
    const float* b1    = (const float*)d_in[7];
    const float* W2    = (const float*)d_in[8];
    const float* b2    = (const float*)d_in[9];
    const float* ln1g  = (const float*)d_in[10];
    const float* ln1b  = (const float*)d_in[11];
    const float* ln2g  = (const float*)d_in[12];
    const float* ln2b  = (const float*)d_in[13];
    float* out = (float*)d_out;

    const size_t M1 = 1048576;
    float* w = (float*)d_ws;
    float* xn   = w;              // 4M floats
    float* qb   = w + 4 * M1;     // 4M
    float* kb   = w + 8 * M1;     // 4M
    float* vb   = w + 12 * M1;    // 4M
    float* attn = w + 16 * M1;    // 4M
    float* x1   = w + 20 * M1;    // 4M
    float* x1n  = w + 24 * M1;    // 4M
    float* hbuf = w + 28 * M1;    // 16M
    float* mst  = w + 44 * M1;            // 64K
    float* lst  = w + 44 * M1 + 65536;    // 64K

    // 1. LN1
    ln_kernel<<<dim3(BT_), dim3(256), 0, stream>>>(x, ln1g, ln1b, xn);
    // 2. QKV
    qkv_kernel<<<dim3(BT_ / 64, H_, 3), dim3(256), 0, stream>>>(
        xn, Wq, Wk, Wv, qb, kb, vb);
    // 3. column-softmax stats
    attn_pass1<<<dim3(T_ / 64, B_ * H_), dim3(256), 0, stream>>>(qb, kb, mst, lst);
    // 4. attention output (concat heads)
    attn_pass2<<<dim3(T_ / 64, B_ * H_), dim3(256), 0, stream>>>(
        qb, kb, vb, mst, lst, attn);
    // 5. proj + bias + residual(xn) -> x1
    gemm64<true, true, false><<<dim3(D_ / 64, BT_ / 64), dim3(256), 0, stream>>>(
        attn, Wproj, bproj, xn, x1, BT_, D_, D_);
    // 6. LN2
    ln_kernel<<<dim3(BT_), dim3(256), 0, stream>>>(x1, ln2g, ln2b, x1n);
    // 7. FFN1: relu(x1n @ W1 + b1)
    gemm64<true, false, true><<<dim3(4 * D_ / 64, BT_ / 64), dim3(256), 0, stream>>>(
        x1n, W1, b1, nullptr, hbuf, BT_, 4 * D_, D_);
    // 8. FFN2: x1n + hbuf @ W2 + b2 -> out
    gemm64<true, true, false><<<dim3(D_ / 64, BT_ / 64), dim3(256), 0, stream>>>(
        hbuf, W2, b2, x1n, out, BT_, D_, 4 * D_);
    (void)in_sizes; (void)n_in; (void)out_size; (void)ws_size;
}

// Round 2
// 1311.223 us; speedup vs baseline: 1.9063x; 1.9063x over previous
//
#include <hip/hip_runtime.h>
#include <math.h>

#define B_ 2
#define T_ 2048
#define D_ 1024
#define H_ 16
#define HS_ 64
#define BT_ (B_*T_)
#define EPS_ 1e-5f
#define SCALE_ 0.03125f  // D^-0.5 = 1/32
#define NEG_ (-1e30f)

typedef __attribute__((ext_vector_type(4))) float f32x4;
typedef __attribute__((ext_vector_type(8))) __bf16 bf16x8;

__device__ __forceinline__ short f2bf(float f) {
    union { float f; unsigned u; } cv; cv.f = f;
    unsigned u = cv.u;
    return (short)((u + 0x7fffu + ((u >> 16) & 1u)) >> 16);  // RTNE
}

// ---------------- LayerNorm: one block per row; fp32 + bf16 outputs --------
__global__ __launch_bounds__(256) void ln_kernel(const float* __restrict__ x,
        const float* __restrict__ g, const float* __restrict__ b,
        float* __restrict__ out, short* __restrict__ outb) {
    int row = blockIdx.x;
    int tid = threadIdx.x;
    const float* xr = x + (size_t)row * D_;
    float4 v = *(const float4*)(xr + tid * 4);
    __shared__ float red[256];
    red[tid] = v.x + v.y + v.z + v.w;
    __syncthreads();
    for (int st = 128; st > 0; st >>= 1) {
        if (tid < st) red[tid] += red[tid + st];
        __syncthreads();
    }
    float mean = red[0] * (1.0f / D_);
    __syncthreads();
    float dx = v.x - mean, dy = v.y - mean, dz = v.z - mean, dw = v.w - mean;
    red[tid] = dx*dx + dy*dy + dz*dz + dw*dw;
    __syncthreads();
    for (int st = 128; st > 0; st >>= 1) {
        if (tid < st) red[tid] += red[tid + st];
        __syncthreads();
    }
    float rstd = rsqrtf(red[0] * (1.0f / D_) + EPS_);
    float4 gv = *(const float4*)(g + tid * 4);
    float4 bv = *(const float4*)(b + tid * 4);
    float4 o;
    o.x = dx * rstd * gv.x + bv.x;
    o.y = dy * rstd * gv.y + bv.y;
    o.z = dz * rstd * gv.z + bv.z;
    o.w = dw * rstd * gv.w + bv.w;
    *(float4*)(out + (size_t)row * D_ + tid * 4) = o;
    short4 ob = make_short4(f2bf(o.x), f2bf(o.y), f2bf(o.z), f2bf(o.w));
    *(short4*)(outb + (size_t)row * D_ + tid * 4) = ob;
}

// ---------------- fp32 [R][C] -> bf16 [C][R] transpose+convert (batched) ---
__global__ __launch_bounds__(256) void transpose_cvt(const float* __restrict__ in,
        short* __restrict__ out, int R, int C) {
    __shared__ float t[32][33];
    int c0 = blockIdx.x * 32, r0 = blockIdx.y * 32;
    const float* inb = in + (size_t)blockIdx.z * R * C;
    short* outb = out + (size_t)blockIdx.z * R * C;
    int tx = threadIdx.x & 31, ty = threadIdx.x >> 5;   // 32 x 8
    #pragma unroll
    for (int i = 0; i < 32; i += 8)
        t[ty + i][tx] = inb[(size_t)(r0 + ty + i) * C + c0 + tx];
    __syncthreads();
    #pragma unroll
    for (int i = 0; i < 32; i += 8)
        outb[(size_t)(c0 + ty + i) * R + r0 + tx] = f2bf(t[tx][ty + i]);
}

// ---------------- fp32 -> bf16 flat convert (8 elems/thread) ---------------
__global__ __launch_bounds__(256) void cvt_bf16(const float* __restrict__ in,
        short* __restrict__ out, int n8) {
    int i = blockIdx.x * 256 + threadIdx.x;
    if (i >= n8) return;
    const float4* p = (const float4*)in + (size_t)i * 2;
    float4 a = p[0], bq = p[1];
    short o[8] = { f2bf(a.x), f2bf(a.y), f2bf(a.z), f2bf(a.w),
                   f2bf(bq.x), f2bf(bq.y), f2bf(bq.z), f2bf(bq.w) };
    *(short4*)(out + (size_t)i * 8 + 0) = make_short4(o[0], o[1], o[2], o[3]);
    *(short4*)(out + (size_t)i * 8 + 4) = make_short4(o[4], o[5], o[6], o[7]);
}

// ---------------- bf16 MFMA GEMM: C[M,N] = A[M,K] @ Bt[N,K]^T --------------
// 128x128 tile, BK=64, 4 waves (2x2), global_load_lds staging, T2 swizzle.
template<bool BIAS, bool RES, bool RELU, bool BF16OUT, bool QKV>
__global__ __launch_bounds__(256) void gemm_mfma(
        const short* __restrict__ A, const short* __restrict__ Bt,
        const float* __restrict__ bias, const float* __restrict__ res,
        float* __restrict__ C, short* __restrict__ Cb,
        float* __restrict__ qo, float* __restrict__ ko, float* __restrict__ vo,
        int M, int N, int K) {
    __shared__ char As[16384];   // [128 rows][64 bf16], XOR-swizzled content
    __shared__ char Bs[16384];
    int tid = threadIdx.x;
    int lane = tid & 63, w = tid >> 6;
    int wr = w >> 1, wc = w & 1;
    int m0 = blockIdx.y * 128, n0 = blockIdx.x * 128;
    f32x4 acc[4][4] = {};

    // staging geometry: chunk c = w*4+i covers LDS [c*1024, c*1024+1024)
    int rowS[4], kbS[4];
    #pragma unroll
    for (int i = 0; i < 4; ++i) {
        int o = (w * 4 + i) * 1024 + lane * 16;
        rowS[i] = o >> 7;                               // tile row 0..127
        kbS[i] = (o & 127) ^ ((rowS[i] & 7) << 4);      // inverse-swizzled src
    }
    const size_t Kb = (size_t)K * 2;

    for (int kt = 0; kt < K; kt += 64) {
        #pragma unroll
        for (int i = 0; i < 4; ++i) {
            int c = w * 4 + i;
            const char* ga = (const char*)A + (size_t)(m0 + rowS[i]) * Kb
                             + (size_t)kt * 2 + kbS[i];
            __builtin_amdgcn_global_load_lds(
                (const __attribute__((address_space(1))) void*)ga,
                (__attribute__((address_space(3))) void*)(As + c * 1024), 16, 0, 0);
            const char* gb = (const char*)Bt + (size_t)(n0 + rowS[i]) * Kb
                             + (size_t)kt * 2 + kbS[i];
            __builtin_amdgcn_global_load_lds(
                (const __attribute__((address_space(1))) void*)gb,
                (__attribute__((address_space(3))) void*)(Bs + c * 1024), 16, 0, 0);
        }
        __syncthreads();   // compiler drains vmcnt before s_barrier
        #pragma unroll
        for (int kk = 0; kk < 2; ++kk) {
            int kbyte = kk * 64 + (lane >> 4) * 16;
            bf16x8 af[4], bf[4];
            #pragma unroll
            for (int mi = 0; mi < 4; ++mi) {
                int row = wr * 64 + mi * 16 + (lane & 15);
                af[mi] = *(const bf16x8*)(As + row * 128 + (kbyte ^ ((row & 7) << 4)));
            }
            #pragma unroll
            for (int ni = 0; ni < 4; ++ni) {
                int row = wc * 64 + ni * 16 + (lane & 15);
                bf[ni] = *(const bf16x8*)(Bs + row * 128 + (kbyte ^ ((row & 7) << 4)));
            }
            #pragma unroll
            for (int mi = 0; mi < 4; ++mi)
                #pragma unroll
                for (int ni = 0; ni < 4; ++ni)
                    acc[mi][ni] = __builtin_amdgcn_mfma_f32_16x16x32_bf16(
                        af[mi], bf[ni], acc[mi][ni], 0, 0, 0);
        }
        __syncthreads();
    }

    // epilogue: C/D layout col=lane&15, row=(lane>>4)*4+reg  [m89-verified]
    #pragma unroll
    for (int mi = 0; mi < 4; ++mi) {
        #pragma unroll
        for (int j = 0; j < 4; ++j) {
            int row = m0 + wr * 64 + mi * 16 + (lane >> 4) * 4 + j;
            #pragma unroll
            for (int ni = 0; ni < 4; ++ni) {
                int col = n0 + wc * 64 + ni * 16 + (lane & 15);
                float vv = acc[mi][ni][j];
                if (BIAS) vv += bias[col];
                if (RES)  vv += res[(size_t)row * N + col];
                if (RELU) vv = fmaxf(vv, 0.0f);
                if (QKV) {
                    int sel = col >> 10, rem = col & 1023;
                    int h = rem >> 6, e = rem & 63;
                    int bb = row >> 11, tt = row & 2047;
                    float* dst = sel == 0 ? qo : sel == 1 ? ko : vo;
                    dst[(((size_t)(bb * H_ + h)) * T_ + tt) * HS_ + e] = vv;
                } else if (BF16OUT) {
                    Cb[(size_t)row * N + col] = f2bf(vv);
                } else {
                    C[(size_t)row * N + col] = vv;
                }
            }
        }
    }
}

// ---------------- Attention pass 1: column (key-axis over q) stats ----------
__global__ __launch_bounds__(256) void attn_pass1(const float* __restrict__ q,
        const float* __restrict__ k, float* __restrict__ mout,
        float* __restrict__ lout) {
    int kt = blockIdx.x;
    int bh = blockIdx.y;
    const float* qb = q + (size_t)bh * T_ * HS_;
    const float* kb = k + (size_t)bh * T_ * HS_;
    __shared__ float Ks[64][65], Qs[64][65];
    __shared__ float red[16][64];
    __shared__ float mcol[64], lcol[64], nm[64];
    int tid = threadIdx.x;
    int tx = tid & 15, ty = tid >> 4;
    #pragma unroll
    for (int i = 0; i < 4; ++i) {
        int idx = tid + i * 256;
        int r = idx >> 4, e4 = (idx & 15) * 4;
        float4 vv = *(const float4*)(kb + (size_t)(kt * 64 + r) * HS_ + e4);
        Ks[r][e4] = vv.x; Ks[r][e4+1] = vv.y; Ks[r][e4+2] = vv.z; Ks[r][e4+3] = vv.w;
    }
    if (tid < 64) { mcol[tid] = NEG_; lcol[tid] = 0.0f; }
    __syncthreads();
    for (int qt = kt; qt < T_ / 64; ++qt) {
        #pragma unroll
        for (int i = 0; i < 4; ++i) {
            int idx = tid + i * 256;
            int r = idx >> 4, e4 = (idx & 15) * 4;
            float4 vv = *(const float4*)(qb + (size_t)(qt * 64 + r) * HS_ + e4);
            Qs[r][e4] = vv.x; Qs[r][e4+1] = vv.y; Qs[r][e4+2] = vv.z; Qs[r][e4+3] = vv.w;
        }
        __syncthreads();
        float s[4][4] = {};
        #pragma unroll 16
        for (int e = 0; e < 64; ++e) {
            float a[4], b[4];
            #pragma unroll
            for (int i = 0; i < 4; ++i) a[i] = Qs[ty * 4 + i][e];
            #pragma unroll
            for (int j = 0; j < 4; ++j) b[j] = Ks[tx * 4 + j][e];
            #pragma unroll
            for (int i = 0; i < 4; ++i)
                #pragma unroll
                for (int j = 0; j < 4; ++j)
                    s[i][j] = fmaf(a[i], b[j], s[i][j]);
        }
        float pm[4];
        #pragma unroll
        for (int j = 0; j < 4; ++j) {
            int kglob = kt * 64 + tx * 4 + j;
            pm[j] = NEG_;
            #pragma unroll
            for (int i = 0; i < 4; ++i) {
                int qglob = qt * 64 + ty * 4 + i;
                s[i][j] = (qglob >= kglob) ? s[i][j] * SCALE_ : NEG_;
                pm[j] = fmaxf(pm[j], s[i][j]);
            }
            red[ty][tx * 4 + j] = pm[j];
        }
        __syncthreads();
        if (tid < 64) {
            float tm = red[0][tid];
            #pragma unroll
            for (int r = 1; r < 16; ++r) tm = fmaxf(tm, red[r][tid]);
            float newm = fmaxf(mcol[tid], tm);
            lcol[tid] *= expf(mcol[tid] - newm);
            mcol[tid] = newm;
            nm[tid] = newm;
        }
        __syncthreads();
        #pragma unroll
        for (int j = 0; j < 4; ++j) {
            float nmv = nm[tx * 4 + j];
            float ps = 0.0f;
            #pragma unroll
            for (int i = 0; i < 4; ++i) ps += expf(s[i][j] - nmv);
            red[ty][tx * 4 + j] = ps;
        }
        __syncthreads();
        if (tid < 64) {
            float sm = 0.0f;
            #pragma unroll
            for (int r = 0; r < 16; ++r) sm += red[r][tid];
            lcol[tid] += sm;
        }
        __syncthreads();
    }
    if (tid < 64) {
        mout[(size_t)bh * T_ + kt * 64 + tid] = mcol[tid];
        lout[(size_t)bh * T_ + kt * 64 + tid] = lcol[tid];
    }
}

// ---------------- Attention pass 2: O = sum_k w[q,k] V[k] -------------------
__global__ __launch_bounds__(256) void attn_pass2(const float* __restrict__ q,
        const float* __restrict__ k, const float* __restrict__ v,
        const float* __restrict__ mio, const float* __restrict__ lio,
        float* __restrict__ attn_cat) {
    int qt = blockIdx.x;
    int bh = blockIdx.y;
    int bb = bh / H_, hh = bh % H_;
    const float* qb = q + (size_t)bh * T_ * HS_;
    const float* kb = k + (size_t)bh * T_ * HS_;
    const float* vb = v + (size_t)bh * T_ * HS_;
    __shared__ float Qs[64][65], Ks[64][65], Vs[64][65];
    __shared__ float mt_[64], lt_[64];
    int tid = threadIdx.x;
    int tx = tid & 15, ty = tid >> 4;
    #pragma unroll
    for (int i = 0; i < 4; ++i) {
        int idx = tid + i * 256;
        int r = idx >> 4, e4 = (idx & 15) * 4;
        float4 vv = *(const float4*)(qb + (size_t)(qt * 64 + r) * HS_ + e4);
        Qs[r][e4] = vv.x; Qs[r][e4+1] = vv.y; Qs[r][e4+2] = vv.z; Qs[r][e4+3] = vv.w;
    }
    float o[4][4] = {};
    for (int kt2 = 0; kt2 <= qt; ++kt2) {
        __syncthreads();
        #pragma unroll
        for (int i = 0; i < 4; ++i) {
            int idx = tid + i * 256;
            int r = idx >> 4, e4 = (idx & 15) * 4;
            float4 kv = *(const float4*)(kb + (size_t)(kt2 * 64 + r) * HS_ + e4);
            Ks[r][e4] = kv.x; Ks[r][e4+1] = kv.y; Ks[r][e4+2] = kv.z; Ks[r][e4+3] = kv.w;
            float4 vv = *(const float4*)(vb + (size_t)(kt2 * 64 + r) * HS_ + e4);
            Vs[r][e4] = vv.x; Vs[r][e4+1] = vv.y; Vs[r][e4+2] = vv.z; Vs[r][e4+3] = vv.w;
        }
        if (tid < 64) {
            mt_[tid] = mio[(size_t)bh * T_ + kt2 * 64 + tid];
            lt_[tid] = 1.0f / lio[(size_t)bh * T_ + kt2 * 64 + tid];
        }
        __syncthreads();
        float s[4][4] = {};
        #pragma unroll 16
        for (int e = 0; e < 64; ++e) {
            float a[4], b[4];
            #pragma unroll
            for (int i = 0; i < 4; ++i) a[i] = Qs[ty * 4 + i][e];
            #pragma unroll
            for (int j = 0; j < 4; ++j) b[j] = Ks[tx * 4 + j][e];
            #pragma unroll
            for (int i = 0; i < 4; ++i)
                #pragma unroll
                for (int j = 0; j < 4; ++j)
                    s[i][j] = fmaf(a[i], b[j], s[i][j]);
        }
        float w[4][4];
        #pragma unroll
        for (int j = 0; j < 4; ++j) {
            int kglob = kt2 * 64 + tx * 4 + j;
            float mv = mt_[tx * 4 + j], lv = lt_[tx * 4 + j];
            #pragma unroll
            for (int i = 0; i < 4; ++i) {
                int qglob = qt * 64 + ty * 4 + i;
                w[i][j] = (qglob >= kglob) ? expf(s[i][j] * SCALE_ - mv) * lv : 0.0f;
            }
        }
        __syncthreads();
        #pragma unroll
        for (int i = 0; i < 4; ++i)
            #pragma unroll
            for (int j = 0; j < 4; ++j)
                Ks[ty * 4 + i][tx * 4 + j] = w[i][j];
        __syncthreads();
        #pragma unroll 8
        for (int kk = 0; kk < 64; ++kk) {
            float wa[4], vb4[4];
            #pragma unroll
            for (int i = 0; i < 4; ++i) wa[i] = Ks[ty * 4 + i][kk];
            #pragma unroll
            for (int j = 0; j < 4; ++j) vb4[j] = Vs[kk][tx * 4 + j];
            #pragma unroll
            for (int i = 0; i < 4; ++i)
                #pragma unroll
                for (int j = 0; j < 4; ++j)
                    o[i][j] = fmaf(wa[i], vb4[j], o[i][j]);
        }
    }
    #pragma unroll
    for (int i = 0; i < 4; ++i) {
        int tt = qt * 64 + ty * 4 + i;
        #pragma unroll
        for (int j = 0; j < 4; ++j) {
            attn_cat[((size_t)(bb * T_ + tt)) * D_ + hh * HS_ + tx * 4 + j] = o[i][j];
        }
    }
}

extern "C" void kernel_launch(void* const* d_in, const int* in_sizes, int n_in,
                              void* d_out, int out_size, void* d_ws, size_t ws_size,
                              hipStream_t stream) {
    const float* x     = (const float*)d_in[0];
    const float* Wq    = (const float*)d_in[1];
    const float* Wk    = (const float*)d_in[2];
    const float* Wv    = (const float*)d_in[3];
    const float* Wproj = (const float*)d_in[4];
    const float* bproj = (const float*)d_in[5];
    const float* W1    = (const float*)d_in[6];
    const float* b1    = (const float*)d_in[7];
    const float* W2    = (const float*)d_in[8];
    const float* b2    = (const float*)d_in[9];
    const float* ln1g  = (const float*)d_in[10];
    const float* ln1b  = (const float*)d_in[11];
    const float* ln2g  = (const float*)d_in[12];
    const float* ln2b  = (const float*)d_in[13];
    float* out = (float*)d_out;

    const size_t MB = 1u << 20;
    char* ws = (char*)d_ws;
    float* xn    = (float*)(ws + 0 * MB);     // 16MB
    short* xnb   = (short*)(ws + 16 * MB);    // 8MB
    float* qb    = (float*)(ws + 24 * MB);    // 16MB
    float* kb    = (float*)(ws + 40 * MB);    // 16MB
    float* vb    = (float*)(ws + 56 * MB);    // 16MB
    float* attn  = (float*)(ws + 72 * MB);    // 16MB
    short* attnb = (short*)(ws + 88 * MB);    // 8MB
    float* x1    = (float*)(ws + 96 * MB);    // 16MB
    float* x1n   = (float*)(ws + 112 * MB);   // 16MB
    short* x1nb  = (short*)(ws + 128 * MB);   // 8MB
    short* hb    = (short*)(ws + 24 * MB);    // 32MB, aliases qb/kb (dead by FFN1)
    short* wqkv  = (short*)(ws + 136 * MB);   // 6MB  [3072][1024]
    short* wprjt = (short*)(ws + 142 * MB);   // 2MB  [1024][1024]
    short* w1t   = (short*)(ws + 144 * MB);   // 8MB  [4096][1024]
    short* w2t   = (short*)(ws + 152 * MB);   // 8MB  [1024][4096]
    float* mst   = (float*)(ws + 160 * MB);
    float* lst   = (float*)(ws + 160 * MB + 262144);

    // 0. weight transpose+convert: Wsel[h][d][e] -> wqkv[(sel*16+h)*64+e][d]
    transpose_cvt<<<dim3(2, 32, 16), 256, 0, stream>>>(Wq, wqkv + (size_t)0 * 1048576, 1024, 64);
    transpose_cvt<<<dim3(2, 32, 16), 256, 0, stream>>>(Wk, wqkv + (size_t)1 * 1048576, 1024, 64);
    transpose_cvt<<<dim3(2, 32, 16), 256, 0, stream>>>(Wv, wqkv + (size_t)2 * 1048576, 1024, 64);
    transpose_cvt<<<dim3(32, 32, 1), 256, 0, stream>>>(Wproj, wprjt, 1024, 1024);
    transpose_cvt<<<dim3(128, 32, 1), 256, 0, stream>>>(W1, w1t, 1024, 4096);
    transpose_cvt<<<dim3(32, 128, 1), 256, 0, stream>>>(W2, w2t, 4096, 1024);

    // 1. LN1 -> xn (fp32) + xnb (bf16)
    ln_kernel<<<dim3(BT_), 256, 0, stream>>>(x, ln1g, ln1b, xn, xnb);
    // 2. QKV fused GEMM [4096 x 3072 x 1024] -> q,k,v fp32 [bh][T][HS]
    gemm_mfma<false, false, false, false, true><<<dim3(24, 32), 256, 0, stream>>>(
        xnb, wqkv, nullptr, nullptr, nullptr, nullptr, qb, kb, vb, BT_, 3072, 1024);
    // 3. column-softmax stats
    attn_pass1<<<dim3(T_ / 64, B_ * H_), 256, 0, stream>>>(qb, kb, mst, lst);
    // 4. attention output (concat heads)
    attn_pass2<<<dim3(T_ / 64, B_ * H_), 256, 0, stream>>>(qb, kb, vb, mst, lst, attn);
    // 5. attn -> bf16
    cvt_bf16<<<dim3(2048), 256, 0, stream>>>(attn, attnb, BT_ * D_ / 8);
    // 6. proj + bias + residual(xn) -> x1
    gemm_mfma<true, true, false, false, false><<<dim3(8, 32), 256, 0, stream>>>(
        attnb, wprjt, bproj, xn, x1, nullptr, nullptr, nullptr, nullptr, BT_, 1024, 1024);
    // 7. LN2 -> x1n + x1nb
    ln_kernel<<<dim3(BT_), 256, 0, stream>>>(x1, ln2g, ln2b, x1n, x1nb);
    // 8. FFN1: relu(x1n @ W1 + b1) -> hb (bf16)
    gemm_mfma<true, false, true, true, false><<<dim3(32, 32), 256, 0, stream>>>(
        x1nb, w1t, b1, nullptr, nullptr, hb, nullptr, nullptr, nullptr, BT_, 4096, 1024);
    // 9. FFN2: x1n + hb @ W2 + b2 -> out
    gemm_mfma<true, true, false, false, false><<<dim3(8, 32), 256, 0, stream>>>(
        hb, w2t, b2, x1n, out, nullptr, nullptr, nullptr, nullptr, BT_, 1024, 4096);
    (void)in_sizes; (void)n_in; (void)out_size; (void)ws_size;
}

// Round 3
// 381.522 us; speedup vs baseline: 6.5517x; 3.4368x over previous
//
#include <hip/hip_runtime.h>
#include <math.h>

#define B_ 2
#define T_ 2048
#define D_ 1024
#define H_ 16
#define HS_ 64
#define BT_ (B_*T_)
#define EPS_ 1e-5f
#define SCALE_ 0.03125f  // D^-0.5 = 1/32
#define NEG_ (-1e30f)
#define C2_ (0.03125f * 1.44269504088896f)   // SCALE * log2(e)

typedef __attribute__((ext_vector_type(4))) float f32x4;
typedef __attribute__((ext_vector_type(8))) __bf16 bf16x8;

__device__ __forceinline__ short f2bf(float f) {
    union { float f; unsigned u; } cv; cv.f = f;
    unsigned u = cv.u;
    return (short)((u + 0x7fffu + ((u >> 16) & 1u)) >> 16);  // RTNE
}

// ---------------- LayerNorm: one block per row; fp32 + bf16 outputs --------
__global__ __launch_bounds__(256) void ln_kernel(const float* __restrict__ x,
        const float* __restrict__ g, const float* __restrict__ b,
        float* __restrict__ out, short* __restrict__ outb) {
    int row = blockIdx.x;
    int tid = threadIdx.x;
    const float* xr = x + (size_t)row * D_;
    float4 v = *(const float4*)(xr + tid * 4);
    __shared__ float red[256];
    red[tid] = v.x + v.y + v.z + v.w;
    __syncthreads();
    for (int st = 128; st > 0; st >>= 1) {
        if (tid < st) red[tid] += red[tid + st];
        __syncthreads();
    }
    float mean = red[0] * (1.0f / D_);
    __syncthreads();
    float dx = v.x - mean, dy = v.y - mean, dz = v.z - mean, dw = v.w - mean;
    red[tid] = dx*dx + dy*dy + dz*dz + dw*dw;
    __syncthreads();
    for (int st = 128; st > 0; st >>= 1) {
        if (tid < st) red[tid] += red[tid + st];
        __syncthreads();
    }
    float rstd = rsqrtf(red[0] * (1.0f / D_) + EPS_);
    float4 gv = *(const float4*)(g + tid * 4);
    float4 bv = *(const float4*)(b + tid * 4);
    float4 o;
    o.x = dx * rstd * gv.x + bv.x;
    o.y = dy * rstd * gv.y + bv.y;
    o.z = dz * rstd * gv.z + bv.z;
    o.w = dw * rstd * gv.w + bv.w;
    *(float4*)(out + (size_t)row * D_ + tid * 4) = o;
    short4 ob = make_short4(f2bf(o.x), f2bf(o.y), f2bf(o.z), f2bf(o.w));
    *(short4*)(outb + (size_t)row * D_ + tid * 4) = ob;
}

// ---------------- fp32 [R][C] -> bf16 [C][R] transpose+convert (batched) ---
__global__ __launch_bounds__(256) void transpose_cvt(const float* __restrict__ in,
        short* __restrict__ out, int R, int C) {
    __shared__ float t[32][33];
    int c0 = blockIdx.x * 32, r0 = blockIdx.y * 32;
    const float* inb = in + (size_t)blockIdx.z * R * C;
    short* outb = out + (size_t)blockIdx.z * R * C;
    int tx = threadIdx.x & 31, ty = threadIdx.x >> 5;   // 32 x 8
    #pragma unroll
    for (int i = 0; i < 32; i += 8)
        t[ty + i][tx] = inb[(size_t)(r0 + ty + i) * C + c0 + tx];
    __syncthreads();
    #pragma unroll
    for (int i = 0; i < 32; i += 8)
        outb[(size_t)(c0 + ty + i) * R + r0 + tx] = f2bf(t[tx][ty + i]);
}

// ---------------- bf16 MFMA GEMM: C[M,N] = A[M,K] @ Bt[N,K]^T --------------
// 128x128 tile, BK=64, 4 waves (2x2), global_load_lds staging, T2 swizzle.
template<bool BIAS, bool RES, bool RELU, bool BF16OUT, bool QKV>
__global__ __launch_bounds__(256) void gemm_mfma(
        const short* __restrict__ A, const short* __restrict__ Bt,
        const float* __restrict__ bias, const float* __restrict__ res,
        float* __restrict__ C, short* __restrict__ Cb,
        short* __restrict__ qo, short* __restrict__ ko, short* __restrict__ vo,
        int M, int N, int K) {
    __shared__ char As[16384];   // [128 rows][64 bf16], XOR-swizzled content
    __shared__ char Bs[16384];
    int tid = threadIdx.x;
    int lane = tid & 63, w = tid >> 6;
    int wr = w >> 1, wc = w & 1;
    int m0 = blockIdx.y * 128, n0 = blockIdx.x * 128;
    f32x4 acc[4][4] = {};

    int rowS[4], kbS[4];
    #pragma unroll
    for (int i = 0; i < 4; ++i) {
        int o = (w * 4 + i) * 1024 + lane * 16;
        rowS[i] = o >> 7;                               // tile row 0..127
        kbS[i] = (o & 127) ^ ((rowS[i] & 7) << 4);      // inverse-swizzled src
    }
    const size_t Kb = (size_t)K * 2;

    for (int kt = 0; kt < K; kt += 64) {
        #pragma unroll
        for (int i = 0; i < 4; ++i) {
            int c = w * 4 + i;
            const char* ga = (const char*)A + (size_t)(m0 + rowS[i]) * Kb
                             + (size_t)kt * 2 + kbS[i];
            __builtin_amdgcn_global_load_lds(
                (const __attribute__((address_space(1))) void*)ga,
                (__attribute__((address_space(3))) void*)(As + c * 1024), 16, 0, 0);
            const char* gb = (const char*)Bt + (size_t)(n0 + rowS[i]) * Kb
                             + (size_t)kt * 2 + kbS[i];
            __builtin_amdgcn_global_load_lds(
                (const __attribute__((address_space(1))) void*)gb,
                (__attribute__((address_space(3))) void*)(Bs + c * 1024), 16, 0, 0);
        }
        __syncthreads();
        #pragma unroll
        for (int kk = 0; kk < 2; ++kk) {
            int kbyte = kk * 64 + (lane >> 4) * 16;
            bf16x8 af[4], bf[4];
            #pragma unroll
            for (int mi = 0; mi < 4; ++mi) {
                int row = wr * 64 + mi * 16 + (lane & 15);
                af[mi] = *(const bf16x8*)(As + row * 128 + (kbyte ^ ((row & 7) << 4)));
            }
            #pragma unroll
            for (int ni = 0; ni < 4; ++ni) {
                int row = wc * 64 + ni * 16 + (lane & 15);
                bf[ni] = *(const bf16x8*)(Bs + row * 128 + (kbyte ^ ((row & 7) << 4)));
            }
            #pragma unroll
            for (int mi = 0; mi < 4; ++mi)
                #pragma unroll
                for (int ni = 0; ni < 4; ++ni)
                    acc[mi][ni] = __builtin_amdgcn_mfma_f32_16x16x32_bf16(
                        af[mi], bf[ni], acc[mi][ni], 0, 0, 0);
        }
        __syncthreads();
    }

    #pragma unroll
    for (int mi = 0; mi < 4; ++mi) {
        #pragma unroll
        for (int j = 0; j < 4; ++j) {
            int row = m0 + wr * 64 + mi * 16 + (lane >> 4) * 4 + j;
            #pragma unroll
            for (int ni = 0; ni < 4; ++ni) {
                int col = n0 + wc * 64 + ni * 16 + (lane & 15);
                float vv = acc[mi][ni][j];
                if (BIAS) vv += bias[col];
                if (RES)  vv += res[(size_t)row * N + col];
                if (RELU) vv = fmaxf(vv, 0.0f);
                if (QKV) {
                    int sel = col >> 10, rem = col & 1023;
                    int h = rem >> 6, e = rem & 63;
                    int bb = row >> 11, tt = row & 2047;
                    short bv = f2bf(vv);
                    if (sel == 0)
                        qo[(((size_t)(bb * H_ + h)) * T_ + tt) * HS_ + e] = bv;
                    else if (sel == 1)
                        ko[(((size_t)(bb * H_ + h)) * T_ + tt) * HS_ + e] = bv;
                    else  // V stored TRANSPOSED: [bh][e][T]
                        vo[(((size_t)(bb * H_ + h)) * HS_ + e) * T_ + tt] = bv;
                } else if (BF16OUT) {
                    Cb[(size_t)row * N + col] = f2bf(vv);
                } else {
                    C[(size_t)row * N + col] = vv;
                }
            }
        }
    }
}

// ---------------- MFMA pass 1: per-key column stats (t = s*SCALE*log2e) ----
// S^T = K.Q^T tiles: C rows = keys -> per-key reduce = shfl butterfly.
__global__ __launch_bounds__(256) void attn_pass1_mfma(
        const short* __restrict__ qg, const short* __restrict__ kg,
        float* __restrict__ mo, float* __restrict__ lo) {
    int kt = blockIdx.x, bh = blockIdx.y;
    int tid = threadIdx.x, lane = tid & 63, w = tid >> 6;
    __shared__ char Qs[8192];
    const size_t base = (size_t)bh * T_ * HS_;
    int kbase = kt * 64 + w * 16;
    bf16x8 af[2];
    {
        const short* kr = kg + base + (size_t)(kbase + (lane & 15)) * HS_ + (lane >> 4) * 8;
        af[0] = *(const bf16x8*)kr;
        af[1] = *(const bf16x8*)(kr + 32);
    }
    float m[4] = {NEG_, NEG_, NEG_, NEG_}, l[4] = {0, 0, 0, 0};
    for (int qt = kt; qt < T_ / 64; ++qt) {
        __syncthreads();   // all waves done with Qs before restaging
        #pragma unroll
        for (int it = 0; it < 2; ++it) {
            int o = it * 4096 + w * 1024 + lane * 16;
            int row = o >> 7;
            int col = (o & 127) ^ ((row & 7) << 4);
            const char* src = (const char*)(qg + base + (size_t)(qt * 64 + row) * HS_) + col;
            __builtin_amdgcn_global_load_lds(
                (const __attribute__((address_space(1))) void*)src,
                (__attribute__((address_space(3))) void*)(Qs + it * 4096 + w * 1024), 16, 0, 0);
        }
        __syncthreads();
        bool diag = (qt == kt);
        float t[4][4];
        #pragma unroll
        for (int sub = 0; sub < 4; ++sub) {
            f32x4 c = {0.f, 0.f, 0.f, 0.f};
            #pragma unroll
            for (int kk = 0; kk < 2; ++kk) {
                int qrow = sub * 16 + (lane & 15);
                int off = (kk * 64 + (lane >> 4) * 16) ^ ((qrow & 7) << 4);
                bf16x8 bq = *(const bf16x8*)(Qs + qrow * 128 + off);
                c = __builtin_amdgcn_mfma_f32_16x16x32_bf16(af[kk], bq, c, 0, 0, 0);
            }
            #pragma unroll
            for (int j = 0; j < 4; ++j) {
                float tv = c[j] * C2_;
                if (diag) {
                    int qgl = qt * 64 + sub * 16 + (lane & 15);
                    int kgl = kbase + (lane >> 4) * 4 + j;
                    if (qgl < kgl) tv = NEG_;
                }
                t[sub][j] = tv;
            }
        }
        #pragma unroll
        for (int j = 0; j < 4; ++j) {
            float tm = fmaxf(fmaxf(t[0][j], t[1][j]), fmaxf(t[2][j], t[3][j]));
            tm = fmaxf(tm, __shfl_xor(tm, 1));
            tm = fmaxf(tm, __shfl_xor(tm, 2));
            tm = fmaxf(tm, __shfl_xor(tm, 4));
            tm = fmaxf(tm, __shfl_xor(tm, 8));
            float mn = fmaxf(m[j], tm);
            float s = exp2f(t[0][j] - mn) + exp2f(t[1][j] - mn)
                    + exp2f(t[2][j] - mn) + exp2f(t[3][j] - mn);
            s += __shfl_xor(s, 1);
            s += __shfl_xor(s, 2);
            s += __shfl_xor(s, 4);
            s += __shfl_xor(s, 8);
            l[j] = l[j] * exp2f(m[j] - mn) + s;
            m[j] = mn;
        }
    }
    if ((lane & 15) == 0) {
        int g = lane >> 4;
        #pragma unroll
        for (int j = 0; j < 4; ++j) {
            mo[(size_t)bh * T_ + kbase + g * 4 + j] = m[j];
            lo[(size_t)bh * T_ + kbase + g * 4 + j] = l[j];
        }
    }
}

// ---------------- MFMA pass 2: O = sum_k exp2(t-m_k)/l_k * V[k] ------------
__global__ __launch_bounds__(256) void attn_pass2_mfma(
        const short* __restrict__ qg, const short* __restrict__ kg,
        const short* __restrict__ vt, const float* __restrict__ mo,
        const float* __restrict__ lo, short* __restrict__ attnb) {
    int qt = blockIdx.x, bh = blockIdx.y;
    int bb = bh >> 4, hh = bh & 15;
    int tid = threadIdx.x, lane = tid & 63, w = tid >> 6;
    __shared__ char Ks[8192], Vs[8192], Ps[8192];
    __shared__ float mlds[64], rlds[64];
    const size_t qkbase = (size_t)bh * T_ * HS_;
    const size_t vtbase = (size_t)bh * HS_ * T_;
    int q0 = qt * 64 + w * 16;
    bf16x8 aq[2];
    {
        const short* qr = qg + qkbase + (size_t)(q0 + (lane & 15)) * HS_ + (lane >> 4) * 8;
        aq[0] = *(const bf16x8*)qr;
        aq[1] = *(const bf16x8*)(qr + 32);
    }
    f32x4 oacc[4] = {};
    for (int kt2 = 0; kt2 <= qt; ++kt2) {
        __syncthreads();   // prev PV done before restaging Ks/Vs/mlds
        #pragma unroll
        for (int it = 0; it < 2; ++it) {
            int o = it * 4096 + w * 1024 + lane * 16;
            int row = o >> 7;
            int col = (o & 127) ^ ((row & 7) << 4);
            const char* srcK = (const char*)(kg + qkbase + (size_t)(kt2 * 64 + row) * HS_) + col;
            __builtin_amdgcn_global_load_lds(
                (const __attribute__((address_space(1))) void*)srcK,
                (__attribute__((address_space(3))) void*)(Ks + it * 4096 + w * 1024), 16, 0, 0);
            const char* srcV = (const char*)(vt + vtbase + (size_t)row * T_) + kt2 * 128 + col;
            __builtin_amdgcn_global_load_lds(
                (const __attribute__((address_space(1))) void*)srcV,
                (__attribute__((address_space(3))) void*)(Vs + it * 4096 + w * 1024), 16, 0, 0);
        }
        if (tid < 64) {
            mlds[tid] = mo[(size_t)bh * T_ + kt2 * 64 + tid];
            rlds[tid] = 1.0f / lo[(size_t)bh * T_ + kt2 * 64 + tid];
        }
        __syncthreads();
        bool diag = (kt2 == qt);
        #pragma unroll
        for (int sub = 0; sub < 4; ++sub) {
            f32x4 c = {0.f, 0.f, 0.f, 0.f};
            #pragma unroll
            for (int kk = 0; kk < 2; ++kk) {
                int krow = sub * 16 + (lane & 15);
                int off = (kk * 64 + (lane >> 4) * 16) ^ ((krow & 7) << 4);
                bf16x8 bk = *(const bf16x8*)(Ks + krow * 128 + off);
                c = __builtin_amdgcn_mfma_f32_16x16x32_bf16(aq[kk], bk, c, 0, 0, 0);
            }
            float mv = mlds[sub * 16 + (lane & 15)];
            float rv = rlds[sub * 16 + (lane & 15)];
            int keyg = kt2 * 64 + sub * 16 + (lane & 15);
            #pragma unroll
            for (int j = 0; j < 4; ++j) {
                float tv = c[j] * C2_;
                int qgl = q0 + (lane >> 4) * 4 + j;
                float wv = (diag && qgl < keyg) ? 0.0f : exp2f(tv - mv) * rv;
                int ql = w * 16 + (lane >> 4) * 4 + j;
                int kb2 = (sub * 16 + (lane & 15)) * 2;
                *(short*)(Ps + ql * 128 + (kb2 ^ ((ql & 7) << 4))) = f2bf(wv);
            }
        }
        // PV: each wave reads only rows it wrote (in-wave DS ordering).
        bf16x8 ap[2];
        #pragma unroll
        for (int kk = 0; kk < 2; ++kk) {
            int ql = w * 16 + (lane & 15);
            int off = (kk * 64 + (lane >> 4) * 16) ^ ((ql & 7) << 4);
            ap[kk] = *(const bf16x8*)(Ps + ql * 128 + off);
        }
        #pragma unroll
        for (int es = 0; es < 4; ++es) {
            #pragma unroll
            for (int kk = 0; kk < 2; ++kk) {
                int erow = es * 16 + (lane & 15);
                int off = (kk * 64 + (lane >> 4) * 16) ^ ((erow & 7) << 4);
                bf16x8 bv = *(const bf16x8*)(Vs + erow * 128 + off);
                oacc[es] = __builtin_amdgcn_mfma_f32_16x16x32_bf16(ap[kk], bv, oacc[es], 0, 0, 0);
            }
        }
    }
    #pragma unroll
    for (int es = 0; es < 4; ++es) {
        #pragma unroll
        for (int j = 0; j < 4; ++j) {
            int qgl = q0 + (lane >> 4) * 4 + j;
            int e = es * 16 + (lane & 15);
            attnb[((size_t)(bb * T_ + qgl)) * D_ + hh * HS_ + e] = f2bf(oacc[es][j]);
        }
    }
}

extern "C" void kernel_launch(void* const* d_in, const int* in_sizes, int n_in,
                              void* d_out, int out_size, void* d_ws, size_t ws_size,
                              hipStream_t stream) {
    const float* x     = (const float*)d_in[0];
    const float* Wq    = (const float*)d_in[1];
    const float* Wk    = (const float*)d_in[2];
    const float* Wv    = (const float*)d_in[3];
    const float* Wproj = (const float*)d_in[4];
    const float* bproj = (const float*)d_in[5];
    const float* W1    = (const float*)d_in[6];
    const float* b1    = (const float*)d_in[7];
    const float* W2    = (const float*)d_in[8];
    const float* b2    = (const float*)d_in[9];
    const float* ln1g  = (const float*)d_in[10];
    const float* ln1b  = (const float*)d_in[11];
    const float* ln2g  = (const float*)d_in[12];
    const float* ln2b  = (const float*)d_in[13];
    float* out = (float*)d_out;

    const size_t MB = 1u << 20;
    char* ws = (char*)d_ws;
    float* xn    = (float*)(ws + 0 * MB);     // 16MB
    short* xnb   = (short*)(ws + 16 * MB);    // 8MB
    short* qbh   = (short*)(ws + 24 * MB);    // 8MB  [bh][T][HS] bf16
    short* kbh   = (short*)(ws + 32 * MB);    // 8MB  [bh][T][HS] bf16
    short* vtb   = (short*)(ws + 40 * MB);    // 8MB  [bh][HS][T] bf16 (transposed)
    short* attnb = (short*)(ws + 48 * MB);    // 8MB
    float* x1    = (float*)(ws + 56 * MB);    // 16MB
    float* x1n   = (float*)(ws + 72 * MB);    // 16MB
    short* x1nb  = (short*)(ws + 88 * MB);    // 8MB
    short* hb    = (short*)(ws + 96 * MB);    // 32MB
    short* wqkv  = (short*)(ws + 128 * MB);   // 6MB  [3072][1024]
    short* wprjt = (short*)(ws + 134 * MB);   // 2MB  [1024][1024]
    short* w1t   = (short*)(ws + 136 * MB);   // 8MB  [4096][1024]
    short* w2t   = (short*)(ws + 144 * MB);   // 8MB  [1024][4096]
    float* mst   = (float*)(ws + 152 * MB);   // 256KB
    float* lst   = (float*)(ws + 152 * MB + 262144);

    // 0. weight transpose+convert
    transpose_cvt<<<dim3(2, 32, 16), 256, 0, stream>>>(Wq, wqkv + (size_t)0 * 1048576, 1024, 64);
    transpose_cvt<<<dim3(2, 32, 16), 256, 0, stream>>>(Wk, wqkv + (size_t)1 * 1048576, 1024, 64);
    transpose_cvt<<<dim3(2, 32, 16), 256, 0, stream>>>(Wv, wqkv + (size_t)2 * 1048576, 1024, 64);
    transpose_cvt<<<dim3(32, 32, 1), 256, 0, stream>>>(Wproj, wprjt, 1024, 1024);
    transpose_cvt<<<dim3(128, 32, 1), 256, 0, stream>>>(W1, w1t, 1024, 4096);
    transpose_cvt<<<dim3(32, 128, 1), 256, 0, stream>>>(W2, w2t, 4096, 1024);

    // 1. LN1 -> xn (fp32) + xnb (bf16)
    ln_kernel<<<dim3(BT_), 256, 0, stream>>>(x, ln1g, ln1b, xn, xnb);
    // 2. QKV fused GEMM -> q,k bf16 [bh][T][HS]; v bf16 transposed [bh][HS][T]
    gemm_mfma<false, false, false, false, true><<<dim3(24, 32), 256, 0, stream>>>(
        xnb, wqkv, nullptr, nullptr, nullptr, nullptr, qbh, kbh, vtb, BT_, 3072, 1024);
    // 3. column-softmax stats (MFMA)
    attn_pass1_mfma<<<dim3(T_ / 64, B_ * H_), 256, 0, stream>>>(qbh, kbh, mst, lst);
    // 4. attention output (MFMA) -> attnb bf16 [B][T][D]
    attn_pass2_mfma<<<dim3(T_ / 64, B_ * H_), 256, 0, stream>>>(
        qbh, kbh, vtb, mst, lst, attnb);
    // 5. proj + bias + residual(xn) -> x1
    gemm_mfma<true, true, false, false, false><<<dim3(8, 32), 256, 0, stream>>>(
        attnb, wprjt, bproj, xn, x1, nullptr, nullptr, nullptr, nullptr, BT_, 1024, 1024);
    // 6. LN2 -> x1n + x1nb
    ln_kernel<<<dim3(BT_), 256, 0, stream>>>(x1, ln2g, ln2b, x1n, x1nb);
    // 7. FFN1: relu(x1n @ W1 + b1) -> hb (bf16)
    gemm_mfma<true, false, true, true, false><<<dim3(32, 32), 256, 0, stream>>>(
        x1nb, w1t, b1, nullptr, nullptr, hb, nullptr, nullptr, nullptr, BT_, 4096, 1024);
    // 8. FFN2: x1n + hb @ W2 + b2 -> out
    gemm_mfma<true, true, false, false, false><<<dim3(8, 32), 256, 0, stream>>>(
        hb, w2t, b2, x1n, out, nullptr, nullptr, nullptr, nullptr, BT_, 1024, 4096);
    (void)in_sizes; (void)n_in; (void)out_size; (void)ws_size;
}

// Round 4
// 361.725 us; speedup vs baseline: 6.9102x; 1.0547x over previous
//
#include <hip/hip_runtime.h>
#include <math.h>

#define B_ 2
#define T_ 2048
#define D_ 1024
#define H_ 16
#define HS_ 64
#define BT_ (B_*T_)
#define EPS_ 1e-5f
#define SCALE_ 0.03125f  // D^-0.5 = 1/32
#define C2_ (0.03125f * 1.44269504088896f)   // SCALE * log2(e)

typedef __attribute__((ext_vector_type(4))) float f32x4;
typedef __attribute__((ext_vector_type(8))) __bf16 bf16x8;

__device__ __forceinline__ short f2bf(float f) {
    union { float f; unsigned u; } cv; cv.f = f;
    unsigned u = cv.u;
    return (short)((u + 0x7fffu + ((u >> 16) & 1u)) >> 16);  // RTNE
}

// ---------------- LayerNorm: one block per row; fp32 + bf16 outputs --------
__global__ __launch_bounds__(256) void ln_kernel(const float* __restrict__ x,
        const float* __restrict__ g, const float* __restrict__ b,
        float* __restrict__ out, short* __restrict__ outb) {
    int row = blockIdx.x;
    int tid = threadIdx.x;
    const float* xr = x + (size_t)row * D_;
    float4 v = *(const float4*)(xr + tid * 4);
    __shared__ float red[256];
    red[tid] = v.x + v.y + v.z + v.w;
    __syncthreads();
    for (int st = 128; st > 0; st >>= 1) {
        if (tid < st) red[tid] += red[tid + st];
        __syncthreads();
    }
    float mean = red[0] * (1.0f / D_);
    __syncthreads();
    float dx = v.x - mean, dy = v.y - mean, dz = v.z - mean, dw = v.w - mean;
    red[tid] = dx*dx + dy*dy + dz*dz + dw*dw;
    __syncthreads();
    for (int st = 128; st > 0; st >>= 1) {
        if (tid < st) red[tid] += red[tid + st];
        __syncthreads();
    }
    float rstd = rsqrtf(red[0] * (1.0f / D_) + EPS_);
    float4 gv = *(const float4*)(g + tid * 4);
    float4 bv = *(const float4*)(b + tid * 4);
    float4 o;
    o.x = dx * rstd * gv.x + bv.x;
    o.y = dy * rstd * gv.y + bv.y;
    o.z = dz * rstd * gv.z + bv.z;
    o.w = dw * rstd * gv.w + bv.w;
    *(float4*)(out + (size_t)row * D_ + tid * 4) = o;
    short4 ob = make_short4(f2bf(o.x), f2bf(o.y), f2bf(o.z), f2bf(o.w));
    *(short4*)(outb + (size_t)row * D_ + tid * 4) = ob;
}

// ---------------- fp32 [R][C] -> bf16 [C][R] transpose+convert (batched) ---
__global__ __launch_bounds__(256) void transpose_cvt(const float* __restrict__ in,
        short* __restrict__ out, int R, int C) {
    __shared__ float t[32][33];
    int c0 = blockIdx.x * 32, r0 = blockIdx.y * 32;
    const float* inb = in + (size_t)blockIdx.z * R * C;
    short* outb = out + (size_t)blockIdx.z * R * C;
    int tx = threadIdx.x & 31, ty = threadIdx.x >> 5;   // 32 x 8
    #pragma unroll
    for (int i = 0; i < 32; i += 8)
        t[ty + i][tx] = inb[(size_t)(r0 + ty + i) * C + c0 + tx];
    __syncthreads();
    #pragma unroll
    for (int i = 0; i < 32; i += 8)
        outb[(size_t)(c0 + ty + i) * R + r0 + tx] = f2bf(t[tx][ty + i]);
}

// ---------------- bf16 MFMA GEMM: C[M,N] = A[M,K] @ Bt[N,K]^T --------------
template<bool BIAS, bool RES, bool RELU, bool BF16OUT, bool QKV>
__global__ __launch_bounds__(256) void gemm_mfma(
        const short* __restrict__ A, const short* __restrict__ Bt,
        const float* __restrict__ bias, const float* __restrict__ res,
        float* __restrict__ C, short* __restrict__ Cb,
        short* __restrict__ qo, short* __restrict__ ko, short* __restrict__ vo,
        int M, int N, int K) {
    __shared__ char As[16384];   // [128 rows][64 bf16], XOR-swizzled content
    __shared__ char Bs[16384];
    int tid = threadIdx.x;
    int lane = tid & 63, w = tid >> 6;
    int wr = w >> 1, wc = w & 1;
    int m0 = blockIdx.y * 128, n0 = blockIdx.x * 128;
    f32x4 acc[4][4] = {};

    int rowS[4], kbS[4];
    #pragma unroll
    for (int i = 0; i < 4; ++i) {
        int o = (w * 4 + i) * 1024 + lane * 16;
        rowS[i] = o >> 7;                               // tile row 0..127
        kbS[i] = (o & 127) ^ ((rowS[i] & 7) << 4);      // inverse-swizzled src
    }
    const size_t Kb = (size_t)K * 2;

    for (int kt = 0; kt < K; kt += 64) {
        #pragma unroll
        for (int i = 0; i < 4; ++i) {
            int c = w * 4 + i;
            const char* ga = (const char*)A + (size_t)(m0 + rowS[i]) * Kb
                             + (size_t)kt * 2 + kbS[i];
            __builtin_amdgcn_global_load_lds(
                (const __attribute__((address_space(1))) void*)ga,
                (__attribute__((address_space(3))) void*)(As + c * 1024), 16, 0, 0);
            const char* gb = (const char*)Bt + (size_t)(n0 + rowS[i]) * Kb
                             + (size_t)kt * 2 + kbS[i];
            __builtin_amdgcn_global_load_lds(
                (const __attribute__((address_space(1))) void*)gb,
                (__attribute__((address_space(3))) void*)(Bs + c * 1024), 16, 0, 0);
        }
        __syncthreads();
        #pragma unroll
        for (int kk = 0; kk < 2; ++kk) {
            int kbyte = kk * 64 + (lane >> 4) * 16;
            bf16x8 af[4], bf[4];
            #pragma unroll
            for (int mi = 0; mi < 4; ++mi) {
                int row = wr * 64 + mi * 16 + (lane & 15);
                af[mi] = *(const bf16x8*)(As + row * 128 + (kbyte ^ ((row & 7) << 4)));
            }
            #pragma unroll
            for (int ni = 0; ni < 4; ++ni) {
                int row = wc * 64 + ni * 16 + (lane & 15);
                bf[ni] = *(const bf16x8*)(Bs + row * 128 + (kbyte ^ ((row & 7) << 4)));
            }
            #pragma unroll
            for (int mi = 0; mi < 4; ++mi)
                #pragma unroll
                for (int ni = 0; ni < 4; ++ni)
                    acc[mi][ni] = __builtin_amdgcn_mfma_f32_16x16x32_bf16(
                        af[mi], bf[ni], acc[mi][ni], 0, 0, 0);
        }
        __syncthreads();
    }

    #pragma unroll
    for (int mi = 0; mi < 4; ++mi) {
        #pragma unroll
        for (int j = 0; j < 4; ++j) {
            int row = m0 + wr * 64 + mi * 16 + (lane >> 4) * 4 + j;
            #pragma unroll
            for (int ni = 0; ni < 4; ++ni) {
                int col = n0 + wc * 64 + ni * 16 + (lane & 15);
                float vv = acc[mi][ni][j];
                if (BIAS) vv += bias[col];
                if (RES)  vv += res[(size_t)row * N + col];
                if (RELU) vv = fmaxf(vv, 0.0f);
                if (QKV) {
                    int sel = col >> 10, rem = col & 1023;
                    int h = rem >> 6, e = rem & 63;
                    int bb = row >> 11, tt = row & 2047;
                    short bv = f2bf(vv);
                    if (sel == 0)
                        qo[(((size_t)(bb * H_ + h)) * T_ + tt) * HS_ + e] = bv;
                    else if (sel == 1)
                        ko[(((size_t)(bb * H_ + h)) * T_ + tt) * HS_ + e] = bv;
                    else  // V stored TRANSPOSED: [bh][e][T]
                        vo[(((size_t)(bb * H_ + h)) * HS_ + e) * T_ + tt] = bv;
                } else if (BF16OUT) {
                    Cb[(size_t)row * N + col] = f2bf(vv);
                } else {
                    C[(size_t)row * N + col] = vv;
                }
            }
        }
    }
}

// ---------------- pass 1: per-key column sums (NO max tracking) ------------
// l_k = sum_{q>=k} exp2(t[q,k]); 128 keys/block, q-range chunked 4-way.
// lpart[chunk][bh][T]
__global__ __launch_bounds__(256) void attn_pass1_mfma(
        const short* __restrict__ qg, const short* __restrict__ kg,
        float* __restrict__ lpart) {
    int kt = blockIdx.x;      // 128-key tile, 0..15
    int chunk = blockIdx.y;   // 0..3
    int bh = blockIdx.z;
    int tid = threadIdx.x, lane = tid & 63, w = tid >> 6;
    __shared__ char Qs[8192];
    const size_t base = (size_t)bh * T_ * HS_;
    int kb0 = kt * 128;
    bf16x8 af[2][2];
    #pragma unroll
    for (int s2 = 0; s2 < 2; ++s2) {
        const short* kr = kg + base
            + (size_t)(kb0 + s2 * 64 + w * 16 + (lane & 15)) * HS_ + (lane >> 4) * 8;
        af[s2][0] = *(const bf16x8*)kr;
        af[s2][1] = *(const bf16x8*)(kr + 32);
    }
    int baseT = kt * 2;
    int R = 32 - baseT;
    int cnt = (R + 3) >> 2;
    int qs = baseT + chunk * cnt;
    int qe = qs + cnt; if (qe > 32) qe = 32;
    float psum[2][4] = {};
    for (int qt = qs; qt < qe; ++qt) {
        __syncthreads();
        #pragma unroll
        for (int it = 0; it < 2; ++it) {
            int o = it * 4096 + w * 1024 + lane * 16;
            int row = o >> 7;
            int col = (o & 127) ^ ((row & 7) << 4);
            const char* src = (const char*)(qg + base + (size_t)(qt * 64 + row) * HS_) + col;
            __builtin_amdgcn_global_load_lds(
                (const __attribute__((address_space(1))) void*)src,
                (__attribute__((address_space(3))) void*)(Qs + it * 4096 + w * 1024), 16, 0, 0);
        }
        __syncthreads();
        #pragma unroll
        for (int sub = 0; sub < 4; ++sub) {
            int qrow = sub * 16 + (lane & 15);
            bf16x8 bq[2];
            #pragma unroll
            for (int kk = 0; kk < 2; ++kk) {
                int off = (kk * 64 + (lane >> 4) * 16) ^ ((qrow & 7) << 4);
                bq[kk] = *(const bf16x8*)(Qs + qrow * 128 + off);
            }
            int qglob = qt * 64 + qrow;
            #pragma unroll
            for (int s2 = 0; s2 < 2; ++s2) {
                f32x4 c = {0.f, 0.f, 0.f, 0.f};
                c = __builtin_amdgcn_mfma_f32_16x16x32_bf16(af[s2][0], bq[0], c, 0, 0, 0);
                c = __builtin_amdgcn_mfma_f32_16x16x32_bf16(af[s2][1], bq[1], c, 0, 0, 0);
                #pragma unroll
                for (int j = 0; j < 4; ++j) {
                    int kglob = kb0 + s2 * 64 + w * 16 + (lane >> 4) * 4 + j;
                    float pe = exp2f(c[j] * C2_);
                    psum[s2][j] += (qglob >= kglob) ? pe : 0.0f;
                }
            }
        }
    }
    #pragma unroll
    for (int s2 = 0; s2 < 2; ++s2)
        #pragma unroll
        for (int j = 0; j < 4; ++j) {
            float v = psum[s2][j];
            v += __shfl_xor(v, 1); v += __shfl_xor(v, 2);
            v += __shfl_xor(v, 4); v += __shfl_xor(v, 8);
            psum[s2][j] = v;
        }
    if ((lane & 15) == 0) {
        #pragma unroll
        for (int s2 = 0; s2 < 2; ++s2)
            #pragma unroll
            for (int j = 0; j < 4; ++j)
                lpart[((size_t)chunk * 32 + bh) * T_
                      + kb0 + s2 * 64 + w * 16 + (lane >> 4) * 4 + j] = psum[s2][j];
    }
}

// ---------------- reduce partials -> reciprocal of column sum --------------
__global__ __launch_bounds__(256) void lreduce(const float* __restrict__ lpart,
        float* __restrict__ rl) {
    int i = blockIdx.x * 256 + threadIdx.x;   // i < 32*2048
    const int S = 32 * T_;
    float s = lpart[i] + lpart[S + i] + lpart[2 * S + i] + lpart[3 * S + i];
    rl[i] = 1.0f / s;
}

// ---------------- pass 2: O = sum_k exp2(t) * rl_k * V[k] ------------------
// 128 queries/block, 8 waves; wave w owns query strip q0 = qt128*128 + w*16.
__global__ __launch_bounds__(512) void attn_pass2_mfma(
        const short* __restrict__ qg, const short* __restrict__ kg,
        const short* __restrict__ vt, const float* __restrict__ rl,
        short* __restrict__ attnb) {
    int qt128 = blockIdx.x, bh = blockIdx.y;
    int bb = bh >> 4, hh = bh & 15;
    int tid = threadIdx.x, lane = tid & 63, w = tid >> 6;   // w 0..7
    __shared__ char Ks[8192], Vs[8192], Ps[16384];
    __shared__ float rlds[64];
    const size_t qkbase = (size_t)bh * T_ * HS_;
    const size_t vtbase = (size_t)bh * HS_ * T_;
    int q0 = qt128 * 128 + w * 16;
    bf16x8 aq[2];
    {
        const short* qr = qg + qkbase + (size_t)(q0 + (lane & 15)) * HS_ + (lane >> 4) * 8;
        aq[0] = *(const bf16x8*)qr;
        aq[1] = *(const bf16x8*)(qr + 32);
    }
    f32x4 oacc[4] = {};
    int myDiag = qt128 * 2 + (w >> 2);
    int ktEnd = qt128 * 2 + 2;
    for (int kt2 = 0; kt2 < ktEnd; ++kt2) {
        __syncthreads();
        {
            int wl = w & 3;
            #pragma unroll
            for (int it = 0; it < 2; ++it) {
                int o = wl * 2048 + it * 1024 + lane * 16;
                int row = o >> 7;
                int col = (o & 127) ^ ((row & 7) << 4);
                const char* src;
                char* dst;
                if (w < 4) {
                    src = (const char*)(kg + qkbase + (size_t)(kt2 * 64 + row) * HS_) + col;
                    dst = Ks + wl * 2048 + it * 1024;
                } else {
                    src = (const char*)(vt + vtbase + (size_t)row * T_) + kt2 * 128 + col;
                    dst = Vs + wl * 2048 + it * 1024;
                }
                __builtin_amdgcn_global_load_lds(
                    (const __attribute__((address_space(1))) void*)src,
                    (__attribute__((address_space(3))) void*)dst, 16, 0, 0);
            }
        }
        if (tid < 64) rlds[tid] = rl[(size_t)bh * T_ + kt2 * 64 + tid];
        __syncthreads();
        bool diag = (kt2 == myDiag);
        bool dead = (kt2 > myDiag);
        #pragma unroll
        for (int sub = 0; sub < 4; ++sub) {
            f32x4 c = {0.f, 0.f, 0.f, 0.f};
            #pragma unroll
            for (int kk = 0; kk < 2; ++kk) {
                int krow = sub * 16 + (lane & 15);
                int off = (kk * 64 + (lane >> 4) * 16) ^ ((krow & 7) << 4);
                bf16x8 bk = *(const bf16x8*)(Ks + krow * 128 + off);
                c = __builtin_amdgcn_mfma_f32_16x16x32_bf16(aq[kk], bk, c, 0, 0, 0);
            }
            float rv = rlds[sub * 16 + (lane & 15)];
            int keyg = kt2 * 64 + sub * 16 + (lane & 15);
            #pragma unroll
            for (int j = 0; j < 4; ++j) {
                int qgl = q0 + (lane >> 4) * 4 + j;
                float wv = exp2f(c[j] * C2_) * rv;
                if ((diag && qgl < keyg) || dead) wv = 0.0f;
                int ql = w * 16 + (lane >> 4) * 4 + j;
                int kb2 = (sub * 16 + (lane & 15)) * 2;
                *(short*)(Ps + ql * 128 + (kb2 ^ ((ql & 7) << 4))) = f2bf(wv);
            }
        }
        bf16x8 ap[2];
        #pragma unroll
        for (int kk = 0; kk < 2; ++kk) {
            int ql = w * 16 + (lane & 15);
            int off = (kk * 64 + (lane >> 4) * 16) ^ ((ql & 7) << 4);
            ap[kk] = *(const bf16x8*)(Ps + ql * 128 + off);
        }
        #pragma unroll
        for (int es = 0; es < 4; ++es) {
            #pragma unroll
            for (int kk = 0; kk < 2; ++kk) {
                int erow = es * 16 + (lane & 15);
                int off = (kk * 64 + (lane >> 4) * 16) ^ ((erow & 7) << 4);
                bf16x8 bv = *(const bf16x8*)(Vs + erow * 128 + off);
                oacc[es] = __builtin_amdgcn_mfma_f32_16x16x32_bf16(ap[kk], bv, oacc[es], 0, 0, 0);
            }
        }
    }
    #pragma unroll
    for (int es = 0; es < 4; ++es) {
        #pragma unroll
        for (int j = 0; j < 4; ++j) {
            int qgl = q0 + (lane >> 4) * 4 + j;
            int e = es * 16 + (lane & 15);
            attnb[((size_t)(bb * T_ + qgl)) * D_ + hh * HS_ + e] = f2bf(oacc[es][j]);
        }
    }
}

extern "C" void kernel_launch(void* const* d_in, const int* in_sizes, int n_in,
                              void* d_out, int out_size, void* d_ws, size_t ws_size,
                              hipStream_t stream) {
    const float* x     = (const float*)d_in[0];
    const float* Wq    = (const float*)d_in[1];
    const float* Wk    = (const float*)d_in[2];
    const float* Wv    = (const float*)d_in[3];
    const float* Wproj = (const float*)d_in[4];
    const float* bproj = (const float*)d_in[5];
    const float* W1    = (const float*)d_in[6];
    const float* b1    = (const float*)d_in[7];
    const float* W2    = (const float*)d_in[8];
    const float* b2    = (const float*)d_in[9];
    const float* ln1g  = (const float*)d_in[10];
    const float* ln1b  = (const float*)d_in[11];
    const float* ln2g  = (const float*)d_in[12];
    const float* ln2b  = (const float*)d_in[13];
    float* out = (float*)d_out;

    const size_t MB = 1u << 20;
    char* ws = (char*)d_ws;
    float* xn    = (float*)(ws + 0 * MB);     // 16MB
    short* xnb   = (short*)(ws + 16 * MB);    // 8MB
    short* qbh   = (short*)(ws + 24 * MB);    // 8MB  [bh][T][HS] bf16
    short* kbh   = (short*)(ws + 32 * MB);    // 8MB  [bh][T][HS] bf16
    short* vtb   = (short*)(ws + 40 * MB);    // 8MB  [bh][HS][T] bf16 (transposed)
    short* attnb = (short*)(ws + 48 * MB);    // 8MB
    float* x1    = (float*)(ws + 56 * MB);    // 16MB
    float* x1n   = (float*)(ws + 72 * MB);    // 16MB
    short* x1nb  = (short*)(ws + 88 * MB);    // 8MB
    short* hb    = (short*)(ws + 96 * MB);    // 32MB
    short* wqkv  = (short*)(ws + 128 * MB);   // 6MB  [3072][1024]
    short* wprjt = (short*)(ws + 134 * MB);   // 2MB  [1024][1024]
    short* w1t   = (short*)(ws + 136 * MB);   // 8MB  [4096][1024]
    short* w2t   = (short*)(ws + 144 * MB);   // 8MB  [1024][4096]
    float* lpart = (float*)(ws + 152 * MB);   // 1MB  [4][32][2048]
    float* rl    = (float*)(ws + 153 * MB);   // 256KB [32][2048]

    // 0. weight transpose+convert
    transpose_cvt<<<dim3(2, 32, 16), 256, 0, stream>>>(Wq, wqkv + (size_t)0 * 1048576, 1024, 64);
    transpose_cvt<<<dim3(2, 32, 16), 256, 0, stream>>>(Wk, wqkv + (size_t)1 * 1048576, 1024, 64);
    transpose_cvt<<<dim3(2, 32, 16), 256, 0, stream>>>(Wv, wqkv + (size_t)2 * 1048576, 1024, 64);
    transpose_cvt<<<dim3(32, 32, 1), 256, 0, stream>>>(Wproj, wprjt, 1024, 1024);
    transpose_cvt<<<dim3(128, 32, 1), 256, 0, stream>>>(W1, w1t, 1024, 4096);
    transpose_cvt<<<dim3(32, 128, 1), 256, 0, stream>>>(W2, w2t, 4096, 1024);

    // 1. LN1 -> xn (fp32) + xnb (bf16)
    ln_kernel<<<dim3(BT_), 256, 0, stream>>>(x, ln1g, ln1b, xn, xnb);
    // 2. QKV fused GEMM -> q,k bf16 [bh][T][HS]; v bf16 transposed [bh][HS][T]
    gemm_mfma<false, false, false, false, true><<<dim3(24, 32), 256, 0, stream>>>(
        xnb, wqkv, nullptr, nullptr, nullptr, nullptr, qbh, kbh, vtb, BT_, 3072, 1024);
    // 3. column sums (no max): partials then reciprocal
    attn_pass1_mfma<<<dim3(16, 4, 32), 256, 0, stream>>>(qbh, kbh, lpart);
    lreduce<<<dim3(32 * T_ / 256), 256, 0, stream>>>(lpart, rl);
    // 4. attention output (MFMA) -> attnb bf16 [B][T][D]
    attn_pass2_mfma<<<dim3(16, 32), 512, 0, stream>>>(qbh, kbh, vtb, rl, attnb);
    // 5. proj + bias + residual(xn) -> x1
    gemm_mfma<true, true, false, false, false><<<dim3(8, 32), 256, 0, stream>>>(
        attnb, wprjt, bproj, xn, x1, nullptr, nullptr, nullptr, nullptr, BT_, 1024, 1024);
    // 6. LN2 -> x1n + x1nb
    ln_kernel<<<dim3(BT_), 256, 0, stream>>>(x1, ln2g, ln2b, x1n, x1nb);
    // 7. FFN1: relu(x1n @ W1 + b1) -> hb (bf16)
    gemm_mfma<true, false, true, true, false><<<dim3(32, 32), 256, 0, stream>>>(
        x1nb, w1t, b1, nullptr, nullptr, hb, nullptr, nullptr, nullptr, BT_, 4096, 1024);
    // 8. FFN2: x1n + hb @ W2 + b2 -> out
    gemm_mfma<true, true, false, false, false><<<dim3(8, 32), 256, 0, stream>>>(
        hb, w2t, b2, x1n, out, nullptr, nullptr, nullptr, nullptr, BT_, 1024, 4096);
    (void)in_sizes; (void)n_in; (void)out_size; (void)ws_size;
}

// Round 5
// 332.095 us; speedup vs baseline: 7.5268x; 1.0892x over previous
//
#include <hip/hip_runtime.h>
#include <math.h>

#define B_ 2
#define T_ 2048
#define D_ 1024
#define H_ 16
#define HS_ 64
#define BT_ (B_*T_)
#define EPS_ 1e-5f
#define SCALE_ 0.03125f  // D^-0.5 = 1/32
#define C2_ (0.03125f * 1.44269504088896f)   // SCALE * log2(e)

typedef __attribute__((ext_vector_type(4))) float f32x4;
typedef __attribute__((ext_vector_type(8))) __bf16 bf16x8;

__device__ __forceinline__ short f2bf(float f) {
    union { float f; unsigned u; } cv; cv.f = f;
    unsigned u = cv.u;
    return (short)((u + 0x7fffu + ((u >> 16) & 1u)) >> 16);  // RTNE
}

// ---------------- LayerNorm: one block per row; fp32 + bf16 outputs --------
__global__ __launch_bounds__(256) void ln_kernel(const float* __restrict__ x,
        const float* __restrict__ g, const float* __restrict__ b,
        float* __restrict__ out, short* __restrict__ outb) {
    int row = blockIdx.x;
    int tid = threadIdx.x;
    const float* xr = x + (size_t)row * D_;
    float4 v = *(const float4*)(xr + tid * 4);
    __shared__ float red[256];
    red[tid] = v.x + v.y + v.z + v.w;
    __syncthreads();
    for (int st = 128; st > 0; st >>= 1) {
        if (tid < st) red[tid] += red[tid + st];
        __syncthreads();
    }
    float mean = red[0] * (1.0f / D_);
    __syncthreads();
    float dx = v.x - mean, dy = v.y - mean, dz = v.z - mean, dw = v.w - mean;
    red[tid] = dx*dx + dy*dy + dz*dz + dw*dw;
    __syncthreads();
    for (int st = 128; st > 0; st >>= 1) {
        if (tid < st) red[tid] += red[tid + st];
        __syncthreads();
    }
    float rstd = rsqrtf(red[0] * (1.0f / D_) + EPS_);
    float4 gv = *(const float4*)(g + tid * 4);
    float4 bv = *(const float4*)(b + tid * 4);
    float4 o;
    o.x = dx * rstd * gv.x + bv.x;
    o.y = dy * rstd * gv.y + bv.y;
    o.z = dz * rstd * gv.z + bv.z;
    o.w = dw * rstd * gv.w + bv.w;
    *(float4*)(out + (size_t)row * D_ + tid * 4) = o;
    short4 ob = make_short4(f2bf(o.x), f2bf(o.y), f2bf(o.z), f2bf(o.w));
    *(short4*)(outb + (size_t)row * D_ + tid * 4) = ob;
}

// ---------------- fp32 [R][C] -> bf16 [C][R] transpose+convert (batched) ---
__global__ __launch_bounds__(256) void transpose_cvt(const float* __restrict__ in,
        short* __restrict__ out, int R, int C) {
    __shared__ float t[32][33];
    int c0 = blockIdx.x * 32, r0 = blockIdx.y * 32;
    const float* inb = in + (size_t)blockIdx.z * R * C;
    short* outb = out + (size_t)blockIdx.z * R * C;
    int tx = threadIdx.x & 31, ty = threadIdx.x >> 5;   // 32 x 8
    #pragma unroll
    for (int i = 0; i < 32; i += 8)
        t[ty + i][tx] = inb[(size_t)(r0 + ty + i) * C + c0 + tx];
    __syncthreads();
    #pragma unroll
    for (int i = 0; i < 32; i += 8)
        outb[(size_t)(c0 + ty + i) * R + r0 + tx] = f2bf(t[tx][ty + i]);
}

// ---------------- bf16 MFMA GEMM: C[M,N] = A[M,K] @ Bt[N,K]^T --------------
template<bool BIAS, bool RES, bool RELU, bool BF16OUT, bool QKV>
__global__ __launch_bounds__(256) void gemm_mfma(
        const short* __restrict__ A, const short* __restrict__ Bt,
        const float* __restrict__ bias, const float* __restrict__ res,
        float* __restrict__ C, short* __restrict__ Cb,
        short* __restrict__ qo, short* __restrict__ ko, short* __restrict__ vo,
        int M, int N, int K) {
    __shared__ char As[16384];   // [128 rows][64 bf16], XOR-swizzled content
    __shared__ char Bs[16384];
    int tid = threadIdx.x;
    int lane = tid & 63, w = tid >> 6;
    int wr = w >> 1, wc = w & 1;
    int m0 = blockIdx.y * 128, n0 = blockIdx.x * 128;
    f32x4 acc[4][4] = {};

    int rowS[4], kbS[4];
    #pragma unroll
    for (int i = 0; i < 4; ++i) {
        int o = (w * 4 + i) * 1024 + lane * 16;
        rowS[i] = o >> 7;                               // tile row 0..127
        kbS[i] = (o & 127) ^ ((rowS[i] & 7) << 4);      // inverse-swizzled src
    }
    const size_t Kb = (size_t)K * 2;

    for (int kt = 0; kt < K; kt += 64) {
        #pragma unroll
        for (int i = 0; i < 4; ++i) {
            int c = w * 4 + i;
            const char* ga = (const char*)A + (size_t)(m0 + rowS[i]) * Kb
                             + (size_t)kt * 2 + kbS[i];
            __builtin_amdgcn_global_load_lds(
                (const __attribute__((address_space(1))) void*)ga,
                (__attribute__((address_space(3))) void*)(As + c * 1024), 16, 0, 0);
            const char* gb = (const char*)Bt + (size_t)(n0 + rowS[i]) * Kb
                             + (size_t)kt * 2 + kbS[i];
            __builtin_amdgcn_global_load_lds(
                (const __attribute__((address_space(1))) void*)gb,
                (__attribute__((address_space(3))) void*)(Bs + c * 1024), 16, 0, 0);
        }
        __syncthreads();
        #pragma unroll
        for (int kk = 0; kk < 2; ++kk) {
            int kbyte = kk * 64 + (lane >> 4) * 16;
            bf16x8 af[4], bf[4];
            #pragma unroll
            for (int mi = 0; mi < 4; ++mi) {
                int row = wr * 64 + mi * 16 + (lane & 15);
                af[mi] = *(const bf16x8*)(As + row * 128 + (kbyte ^ ((row & 7) << 4)));
            }
            #pragma unroll
            for (int ni = 0; ni < 4; ++ni) {
                int row = wc * 64 + ni * 16 + (lane & 15);
                bf[ni] = *(const bf16x8*)(Bs + row * 128 + (kbyte ^ ((row & 7) << 4)));
            }
            #pragma unroll
            for (int mi = 0; mi < 4; ++mi)
                #pragma unroll
                for (int ni = 0; ni < 4; ++ni)
                    acc[mi][ni] = __builtin_amdgcn_mfma_f32_16x16x32_bf16(
                        af[mi], bf[ni], acc[mi][ni], 0, 0, 0);
        }
        __syncthreads();
    }

    #pragma unroll
    for (int mi = 0; mi < 4; ++mi) {
        #pragma unroll
        for (int j = 0; j < 4; ++j) {
            int row = m0 + wr * 64 + mi * 16 + (lane >> 4) * 4 + j;
            #pragma unroll
            for (int ni = 0; ni < 4; ++ni) {
                int col = n0 + wc * 64 + ni * 16 + (lane & 15);
                float vv = acc[mi][ni][j];
                if (BIAS) vv += bias[col];
                if (RES)  vv += res[(size_t)row * N + col];
                if (RELU) vv = fmaxf(vv, 0.0f);
                if (QKV) {
                    int sel = col >> 10, rem = col & 1023;
                    int h = rem >> 6, e = rem & 63;
                    int bb = row >> 11, tt = row & 2047;
                    short bv = f2bf(vv);
                    if (sel == 0)
                        qo[(((size_t)(bb * H_ + h)) * T_ + tt) * HS_ + e] = bv;
                    else if (sel == 1)
                        ko[(((size_t)(bb * H_ + h)) * T_ + tt) * HS_ + e] = bv;
                    else  // V stored TRANSPOSED: [bh][e][T]
                        vo[(((size_t)(bb * H_ + h)) * HS_ + e) * T_ + tt] = bv;
                } else if (BF16OUT) {
                    Cb[(size_t)row * N + col] = f2bf(vv);
                } else {
                    C[(size_t)row * N + col] = vv;
                }
            }
        }
    }
}

// ---------------- pass 1: per-key column sums (NO max tracking) ------------
__global__ __launch_bounds__(256) void attn_pass1_mfma(
        const short* __restrict__ qg, const short* __restrict__ kg,
        float* __restrict__ lpart) {
    int kt = blockIdx.x;      // 128-key tile, 0..15
    int chunk = blockIdx.y;   // 0..3
    int bh = blockIdx.z;
    int tid = threadIdx.x, lane = tid & 63, w = tid >> 6;
    __shared__ char Qs[8192];
    const size_t base = (size_t)bh * T_ * HS_;
    int kb0 = kt * 128;
    bf16x8 af[2][2];
    #pragma unroll
    for (int s2 = 0; s2 < 2; ++s2) {
        const short* kr = kg + base
            + (size_t)(kb0 + s2 * 64 + w * 16 + (lane & 15)) * HS_ + (lane >> 4) * 8;
        af[s2][0] = *(const bf16x8*)kr;
        af[s2][1] = *(const bf16x8*)(kr + 32);
    }
    int baseT = kt * 2;
    int R = 32 - baseT;
    int cnt = (R + 3) >> 2;
    int qs = baseT + chunk * cnt;
    int qe = qs + cnt; if (qe > 32) qe = 32;
    float psum[2][4] = {};
    for (int qt = qs; qt < qe; ++qt) {
        __syncthreads();
        #pragma unroll
        for (int it = 0; it < 2; ++it) {
            int o = it * 4096 + w * 1024 + lane * 16;
            int row = o >> 7;
            int col = (o & 127) ^ ((row & 7) << 4);
            const char* src = (const char*)(qg + base + (size_t)(qt * 64 + row) * HS_) + col;
            __builtin_amdgcn_global_load_lds(
                (const __attribute__((address_space(1))) void*)src,
                (__attribute__((address_space(3))) void*)(Qs + it * 4096 + w * 1024), 16, 0, 0);
        }
        __syncthreads();
        #pragma unroll
        for (int sub = 0; sub < 4; ++sub) {
            int qrow = sub * 16 + (lane & 15);
            bf16x8 bq[2];
            #pragma unroll
            for (int kk = 0; kk < 2; ++kk) {
                int off = (kk * 64 + (lane >> 4) * 16) ^ ((qrow & 7) << 4);
                bq[kk] = *(const bf16x8*)(Qs + qrow * 128 + off);
            }
            int qglob = qt * 64 + qrow;
            #pragma unroll
            for (int s2 = 0; s2 < 2; ++s2) {
                f32x4 c = {0.f, 0.f, 0.f, 0.f};
                c = __builtin_amdgcn_mfma_f32_16x16x32_bf16(af[s2][0], bq[0], c, 0, 0, 0);
                c = __builtin_amdgcn_mfma_f32_16x16x32_bf16(af[s2][1], bq[1], c, 0, 0, 0);
                #pragma unroll
                for (int j = 0; j < 4; ++j) {
                    int kglob = kb0 + s2 * 64 + w * 16 + (lane >> 4) * 4 + j;
                    float pe = exp2f(c[j] * C2_);
                    psum[s2][j] += (qglob >= kglob) ? pe : 0.0f;
                }
            }
        }
    }
    #pragma unroll
    for (int s2 = 0; s2 < 2; ++s2)
        #pragma unroll
        for (int j = 0; j < 4; ++j) {
            float v = psum[s2][j];
            v += __shfl_xor(v, 1); v += __shfl_xor(v, 2);
            v += __shfl_xor(v, 4); v += __shfl_xor(v, 8);
            psum[s2][j] = v;
        }
    if ((lane & 15) == 0) {
        #pragma unroll
        for (int s2 = 0; s2 < 2; ++s2)
            #pragma unroll
            for (int j = 0; j < 4; ++j)
                lpart[((size_t)chunk * 32 + bh) * T_
                      + kb0 + s2 * 64 + w * 16 + (lane >> 4) * 4 + j] = psum[s2][j];
    }
}

// ---------------- reduce partials -> reciprocal of column sum --------------
__global__ __launch_bounds__(256) void lreduce(const float* __restrict__ lpart,
        float* __restrict__ rl) {
    int i = blockIdx.x * 256 + threadIdx.x;   // i < 32*2048
    const int S = 32 * T_;
    float s = lpart[i] + lpart[S + i] + lpart[2 * S + i] + lpart[3 * S + i];
    rl[i] = 1.0f / s;
}

// ---------------- pass 2: O = sum_k exp2(t) * rl_k * V[k] ------------------
// Triangle-paired: block handles qtile=pair and qtile=31-pair (64 q each,
// 4 waves). 128-key steps, double-buffered K/V staging. 17 steps/block.
__global__ __launch_bounds__(256) void attn_pass2_mfma(
        const short* __restrict__ qg, const short* __restrict__ kg,
        const short* __restrict__ vt, const float* __restrict__ rl,
        short* __restrict__ attnb) {
    int pair = blockIdx.x, bh = blockIdx.y;
    int bb = bh >> 4, hh = bh & 15;
    int tid = threadIdx.x, lane = tid & 63, w = tid >> 6;   // 4 waves
    __shared__ char Kb[2][16384];   // [128 keys][128B], swizzled
    __shared__ char Vb[2][16384];   // [64 e][256B], swizzled per 128B half
    __shared__ char Ps[8192];       // [64 q][128B], wave-private rows
    __shared__ float rlds[2][128];
    const size_t qkbase = (size_t)bh * T_ * HS_;
    const size_t vtbase = (size_t)bh * HS_ * T_;

    #pragma unroll 1
    for (int half = 0; half < 2; ++half) {
        int qtile = half == 0 ? pair : 31 - pair;
        int q0 = qtile * 64 + w * 16;
        bf16x8 aq[2];
        {
            const short* qr = qg + qkbase + (size_t)(q0 + (lane & 15)) * HS_ + (lane >> 4) * 8;
            aq[0] = *(const bf16x8*)qr;
            aq[1] = *(const bf16x8*)(qr + 32);
        }
        f32x4 oacc[4] = {};
        int nkeys = qtile * 64 + 64;
        int nstep = (nkeys + 127) >> 7;

        // ---- STAGE(buf, step): issue K/V/rl loads for 128-key step ----
        #define STAGE_P2(bufi, stepi) do {                                        \
            int k0_ = (stepi) * 128;                                              \
            _Pragma("unroll")                                                     \
            for (int i_ = 0; i_ < 4; ++i_) {                                      \
                int c_ = w * 4 + i_;                                              \
                int o_ = c_ * 1024 + lane * 16;                                   \
                int krow_ = o_ >> 7;                                              \
                int kcol_ = (o_ & 127) ^ ((krow_ & 7) << 4);                      \
                const char* srcK_ = (const char*)(kg + qkbase                     \
                    + (size_t)(k0_ + krow_) * HS_) + kcol_;                       \
                __builtin_amdgcn_global_load_lds(                                 \
                    (const __attribute__((address_space(1))) void*)srcK_,         \
                    (__attribute__((address_space(3))) void*)(Kb[bufi] + c_ * 1024), \
                    16, 0, 0);                                                    \
                int vrow_ = o_ >> 8;                                              \
                int vcol_ = (o_ & 255) ^ ((vrow_ & 7) << 4);                      \
                const char* srcV_ = (const char*)(vt + vtbase                     \
                    + (size_t)vrow_ * T_ + (size_t)k0_) + vcol_;                  \
                __builtin_amdgcn_global_load_lds(                                 \
                    (const __attribute__((address_space(1))) void*)srcV_,         \
                    (__attribute__((address_space(3))) void*)(Vb[bufi] + c_ * 1024), \
                    16, 0, 0);                                                    \
            }                                                                     \
            if (tid < 128) rlds[bufi][tid] = rl[(size_t)bh * T_ + k0_ + tid];     \
        } while (0)

        STAGE_P2(0, 0);
        __syncthreads();
        for (int st = 0; st < nstep; ++st) {
            int cur = st & 1;
            if (st + 1 < nstep) STAGE_P2(cur ^ 1, st + 1);
            #pragma unroll
            for (int sub64 = 0; sub64 < 2; ++sub64) {
                int k64 = st * 2 + sub64;
                int kbase = k64 * 64;
                if (kbase >= nkeys) break;
                bool diag = (k64 == qtile);
                const char* Ks = Kb[cur] + sub64 * 8192;
                #pragma unroll
                for (int sub = 0; sub < 4; ++sub) {
                    int krow = sub * 16 + (lane & 15);
                    f32x4 c = {0.f, 0.f, 0.f, 0.f};
                    #pragma unroll
                    for (int kk = 0; kk < 2; ++kk) {
                        int off = (kk * 64 + (lane >> 4) * 16) ^ ((krow & 7) << 4);
                        bf16x8 bk = *(const bf16x8*)(Ks + krow * 128 + off);
                        c = __builtin_amdgcn_mfma_f32_16x16x32_bf16(aq[kk], bk, c, 0, 0, 0);
                    }
                    float rv = rlds[cur][sub64 * 64 + sub * 16 + (lane & 15)];
                    int keyg = kbase + sub * 16 + (lane & 15);
                    #pragma unroll
                    for (int j = 0; j < 4; ++j) {
                        int qgl = q0 + (lane >> 4) * 4 + j;
                        float wv = exp2f(c[j] * C2_) * rv;
                        if (diag && qgl < keyg) wv = 0.0f;
                        int ql = w * 16 + (lane >> 4) * 4 + j;
                        int kb2 = (sub * 16 + (lane & 15)) * 2;
                        *(short*)(Ps + ql * 128 + (kb2 ^ ((ql & 7) << 4))) = f2bf(wv);
                    }
                }
                bf16x8 ap[2];
                #pragma unroll
                for (int kk = 0; kk < 2; ++kk) {
                    int ql = w * 16 + (lane & 15);
                    int off = (kk * 64 + (lane >> 4) * 16) ^ ((ql & 7) << 4);
                    ap[kk] = *(const bf16x8*)(Ps + ql * 128 + off);
                }
                #pragma unroll
                for (int es = 0; es < 4; ++es) {
                    int erow = es * 16 + (lane & 15);
                    #pragma unroll
                    for (int kk = 0; kk < 2; ++kk) {
                        int vcol = (sub64 * 128 + kk * 64 + (lane >> 4) * 16) ^ ((erow & 7) << 4);
                        bf16x8 bv = *(const bf16x8*)(Vb[cur] + erow * 256 + vcol);
                        oacc[es] = __builtin_amdgcn_mfma_f32_16x16x32_bf16(ap[kk], bv, oacc[es], 0, 0, 0);
                    }
                }
            }
            __syncthreads();
        }
        #undef STAGE_P2
        #pragma unroll
        for (int es = 0; es < 4; ++es) {
            #pragma unroll
            for (int j = 0; j < 4; ++j) {
                int qgl = q0 + (lane >> 4) * 4 + j;
                int e = es * 16 + (lane & 15);
                attnb[((size_t)(bb * T_ + qgl)) * D_ + hh * HS_ + e] = f2bf(oacc[es][j]);
            }
        }
        __syncthreads();   // LDS safe before next half
    }
}

extern "C" void kernel_launch(void* const* d_in, const int* in_sizes, int n_in,
                              void* d_out, int out_size, void* d_ws, size_t ws_size,
                              hipStream_t stream) {
    const float* x     = (const float*)d_in[0];
    const float* Wq    = (const float*)d_in[1];
    const float* Wk    = (const float*)d_in[2];
    const float* Wv    = (const float*)d_in[3];
    const float* Wproj = (const float*)d_in[4];
    const float* bproj = (const float*)d_in[5];
    const float* W1    = (const float*)d_in[6];
    const float* b1    = (const float*)d_in[7];
    const float* W2    = (const float*)d_in[8];
    const float* b2    = (const float*)d_in[9];
    const float* ln1g  = (const float*)d_in[10];
    const float* ln1b  = (const float*)d_in[11];
    const float* ln2g  = (const float*)d_in[12];
    const float* ln2b  = (const float*)d_in[13];
    float* out = (float*)d_out;

    const size_t MB = 1u << 20;
    char* ws = (char*)d_ws;
    float* xn    = (float*)(ws + 0 * MB);     // 16MB
    short* xnb   = (short*)(ws + 16 * MB);    // 8MB
    short* qbh   = (short*)(ws + 24 * MB);    // 8MB  [bh][T][HS] bf16
    short* kbh   = (short*)(ws + 32 * MB);    // 8MB  [bh][T][HS] bf16
    short* vtb   = (short*)(ws + 40 * MB);    // 8MB  [bh][HS][T] bf16 (transposed)
    short* attnb = (short*)(ws + 48 * MB);    // 8MB
    float* x1    = (float*)(ws + 56 * MB);    // 16MB
    float* x1n   = (float*)(ws + 72 * MB);    // 16MB
    short* x1nb  = (short*)(ws + 88 * MB);    // 8MB
    short* hb    = (short*)(ws + 96 * MB);    // 32MB
    short* wqkv  = (short*)(ws + 128 * MB);   // 6MB  [3072][1024]
    short* wprjt = (short*)(ws + 134 * MB);   // 2MB  [1024][1024]
    short* w1t   = (short*)(ws + 136 * MB);   // 8MB  [4096][1024]
    short* w2t   = (short*)(ws + 144 * MB);   // 8MB  [1024][4096]
    float* lpart = (float*)(ws + 152 * MB);   // 1MB  [4][32][2048]
    float* rl    = (float*)(ws + 153 * MB);   // 256KB [32][2048]

    // 0. weight transpose+convert
    transpose_cvt<<<dim3(2, 32, 16), 256, 0, stream>>>(Wq, wqkv + (size_t)0 * 1048576, 1024, 64);
    transpose_cvt<<<dim3(2, 32, 16), 256, 0, stream>>>(Wk, wqkv + (size_t)1 * 1048576, 1024, 64);
    transpose_cvt<<<dim3(2, 32, 16), 256, 0, stream>>>(Wv, wqkv + (size_t)2 * 1048576, 1024, 64);
    transpose_cvt<<<dim3(32, 32, 1), 256, 0, stream>>>(Wproj, wprjt, 1024, 1024);
    transpose_cvt<<<dim3(128, 32, 1), 256, 0, stream>>>(W1, w1t, 1024, 4096);
    transpose_cvt<<<dim3(32, 128, 1), 256, 0, stream>>>(W2, w2t, 4096, 1024);

    // 1. LN1 -> xn (fp32) + xnb (bf16)
    ln_kernel<<<dim3(BT_), 256, 0, stream>>>(x, ln1g, ln1b, xn, xnb);
    // 2. QKV fused GEMM -> q,k bf16 [bh][T][HS]; v bf16 transposed [bh][HS][T]
    gemm_mfma<false, false, false, false, true><<<dim3(24, 32), 256, 0, stream>>>(
        xnb, wqkv, nullptr, nullptr, nullptr, nullptr, qbh, kbh, vtb, BT_, 3072, 1024);
    // 3. column sums (no max): partials then reciprocal
    attn_pass1_mfma<<<dim3(16, 4, 32), 256, 0, stream>>>(qbh, kbh, lpart);
    lreduce<<<dim3(32 * T_ / 256), 256, 0, stream>>>(lpart, rl);
    // 4. attention output (MFMA, triangle-paired) -> attnb bf16 [B][T][D]
    attn_pass2_mfma<<<dim3(16, 32), 256, 0, stream>>>(qbh, kbh, vtb, rl, attnb);
    // 5. proj + bias + residual(xn) -> x1
    gemm_mfma<true, true, false, false, false><<<dim3(8, 32), 256, 0, stream>>>(
        attnb, wprjt, bproj, xn, x1, nullptr, nullptr, nullptr, nullptr, BT_, 1024, 1024);
    // 6. LN2 -> x1n + x1nb
    ln_kernel<<<dim3(BT_), 256, 0, stream>>>(x1, ln2g, ln2b, x1n, x1nb);
    // 7. FFN1: relu(x1n @ W1 + b1) -> hb (bf16)
    gemm_mfma<true, false, true, true, false><<<dim3(32, 32), 256, 0, stream>>>(
        x1nb, w1t, b1, nullptr, nullptr, hb, nullptr, nullptr, nullptr, BT_, 4096, 1024);
    // 8. FFN2: x1n + hb @ W2 + b2 -> out
    gemm_mfma<true, true, false, false, false><<<dim3(8, 32), 256, 0, stream>>>(
        hb, w2t, b2, x1n, out, nullptr, nullptr, nullptr, nullptr, BT_, 1024, 4096);
    (void)in_sizes; (void)n_in; (void)out_size; (void)ws_size;
}